// Round 4
// baseline (361.262 us; speedup 1.0000x reference)
//
#include <hip/hip_runtime.h>
#include <math.h>

#define B 8
#define T 128
#define I_TOK 196
#define TEXT_DIM 768
#define IMAGE_DIM 1024
#define HIDDEN 512
#define EXP_SCALE 2.88539008177792681f   // 2*log2(e): exp(2x) = 2^(EXP_SCALE*x)

#if __has_builtin(__builtin_amdgcn_exp2f)
#define FAST_EXP2(x) __builtin_amdgcn_exp2f(x)
#else
#define FAST_EXP2(x) exp2f(x)
#endif
#if __has_builtin(__builtin_amdgcn_rcpf)
#define FAST_RCP(x) __builtin_amdgcn_rcpf(x)
#else
#define FAST_RCP(x) __fdividef(1.f, (x))
#endif

typedef short bf16x8 __attribute__((ext_vector_type(8)));
typedef float f32x4 __attribute__((ext_vector_type(4)));

typedef __attribute__((address_space(3))) void       as3_void;
typedef __attribute__((address_space(1))) const void as1_cvoid;

// ---- fragment-tiled layout geometry ---------------------------------------
#define KT_T (TEXT_DIM / 32)     // 24 k-tiles (text)
#define KT_I (IMAGE_DIM / 32)    // 32 k-tiles (image)
#define MT_T (B * T / 16)        // 64 m-tiles (text rows)
#define MT_I (B * I_TOK / 16)    // 98 m-tiles (image rows)
#define NT   (HIDDEN / 16)       // 32 n-tiles (W columns)

#define XT_ELEMS (MT_T * KT_T * 512)       // 786432
#define XI_ELEMS (MT_I * KT_I * 512)       // 1605632
#define X_ELEMS  (XT_ELEMS + XI_ELEMS)
#define WT_T_ELEMS (NT * KT_T * 512)       // 393216
#define W_ELEMS (WT_T_ELEMS + NT * KT_I * 512)

#define XTILES_T (MT_T * KT_T)             // 1536
#define XTILES   (XTILES_T + MT_I * KT_I)  // 4672
#define WTILES_T (NT * KT_T)               // 768
#define WTILES   (WTILES_T + NT * KT_I)    // 1792
#define ALL_TILES (XTILES + WTILES)        // 6464

#define GT2_BLOCKS (16 * 8)                  // 128 (text: 16 m-groups x 8 n)
#define GI2_BLOCKS (25 * 8)                  // 200 (image: 25 m-groups x 8 n)
#define GEMM_GRID (GT2_BLOCKS + GI2_BLOCKS)  // 328

#define ATT_P1_BLOCKS 256                    // 8b * 16 grp * 2 csplit
#define ATT_P2_BLOCKS (B * 28)               // 196 = 28 * 7
#define ATT_GRID (ATT_P1_BLOCKS + ATT_P2_BLOCKS)   // 480

#define MEGA_GRID 512                        // 2 blocks/CU guaranteed resident

__device__ __forceinline__ unsigned short f2bf(float x) {
    unsigned int u = __float_as_uint(x);
    unsigned int r = u + 0x7FFFu + ((u >> 16) & 1u);   // RNE
    return (unsigned short)(r >> 16);
}
__device__ __forceinline__ float bf2f(unsigned short h) {
    return __uint_as_float(((unsigned int)h) << 16);
}

// ---------------- device-scope grid barrier --------------------------------
// Correct under G16: all MEGA_GRID blocks are co-resident by construction
// (512 blocks, 32KB LDS -> 2 blocks/CU, VGPR capped by launch_bounds), so
// spin cannot deadlock. Release: __threadfence (agent fence -> L2 wb) before
// device-scope atomicAdd; acquire: relaxed agent-scope poll + trailing
// __threadfence (L1/L2 inv) by all threads.
__device__ __forceinline__ void grid_barrier(unsigned int* bar, int ph) {
    __syncthreads();
    if (threadIdx.x == 0) {
        __threadfence();
        atomicAdd(&bar[ph], 1u);
        while (__hip_atomic_load(&bar[ph], __ATOMIC_RELAXED, __HIP_MEMORY_SCOPE_AGENT)
               < (unsigned int)MEGA_GRID)
            __builtin_amdgcn_s_sleep(2);
    }
    __syncthreads();
    __threadfence();
}

// ---------------- phase A: prep (split-bf16 + fragment-tiling) -------------
__device__ __forceinline__ void prep_tile(const int id,
        const float* __restrict__ text, const float* __restrict__ image,
        const float* __restrict__ Wt, const float* __restrict__ Wi,
        unsigned short* __restrict__ Xh, unsigned short* __restrict__ Xl,
        unsigned short* __restrict__ WTh, unsigned short* __restrict__ WTl)
{
    const int lane = threadIdx.x & 63;
    const int r16 = lane & 15, quad = lane >> 4;

    float v[8];
    unsigned short* oh;
    unsigned short* ol;
    long dst;

    if (id < XTILES) {
        const float* X; int K, mt, kt;
        if (id < XTILES_T) { X = text; K = TEXT_DIM; mt = id / KT_T; kt = id % KT_T; }
        else { const int i2 = id - XTILES_T; X = image; K = IMAGE_DIM; mt = i2 / KT_I; kt = i2 % KT_I; }
        const float* src = X + (long)(mt * 16 + r16) * K + kt * 32 + quad * 8;
        const float4 a = *(const float4*)src;
        const float4 b = *(const float4*)(src + 4);
        v[0]=a.x; v[1]=a.y; v[2]=a.z; v[3]=a.w; v[4]=b.x; v[5]=b.y; v[6]=b.z; v[7]=b.w;
        oh = (id < XTILES_T) ? Xh : Xh + XT_ELEMS;
        ol = (id < XTILES_T) ? Xl : Xl + XT_ELEMS;
        const long tile = (id < XTILES_T) ? id : (long)(id - XTILES_T);
        dst = tile * 512 + lane * 8;
    } else {
        const int idw = id - XTILES;
        const float* W; int K, nt, kt;
        if (idw < WTILES_T) { W = Wt; K = TEXT_DIM; nt = idw / KT_T; kt = idw % KT_T; }
        else { const int i2 = idw - WTILES_T; W = Wi; K = IMAGE_DIM; nt = i2 / KT_I; kt = i2 % KT_I; }
        const float* src = W + (long)(kt * 32 + quad * 8) * HIDDEN + nt * 16 + r16;
        #pragma unroll
        for (int j = 0; j < 8; ++j) v[j] = src[(long)j * HIDDEN];
        oh = (idw < WTILES_T) ? WTh : WTh + WT_T_ELEMS;
        ol = (idw < WTILES_T) ? WTl : WTl + WT_T_ELEMS;
        const long tile = (idw < WTILES_T) ? idw : (long)(idw - WTILES_T);
        dst = tile * 512 + lane * 8;
    }

    uint4 hv, lv;
    unsigned int hh[8], ll[8];
    #pragma unroll
    for (int j = 0; j < 8; ++j) {
        hh[j] = f2bf(v[j]);
        ll[j] = f2bf(v[j] - bf2f((unsigned short)hh[j]));
    }
    hv.x = hh[0] | (hh[1] << 16); hv.y = hh[2] | (hh[3] << 16);
    hv.z = hh[4] | (hh[5] << 16); hv.w = hh[6] | (hh[7] << 16);
    lv.x = ll[0] | (ll[1] << 16); lv.y = ll[2] | (ll[3] << 16);
    lv.z = ll[4] | (ll[5] << 16); lv.w = ll[6] | (ll[7] << 16);
    *(uint4*)(oh + dst) = hv;
    *(uint4*)(ol + dst) = lv;
}

// ---------------- phase B: MFMA projections (64x64 LDS-staged) -------------
__device__ __forceinline__ void proj_block(const int bid0,
        unsigned short (*lds)[16][512],
        const unsigned short* __restrict__ Xh, const unsigned short* __restrict__ Xl,
        const unsigned short* __restrict__ WTh, const unsigned short* __restrict__ WTl,
        const float* __restrict__ bt, const float* __restrict__ bi,
        float* __restrict__ pt, float* __restrict__ pi)
{
    const int tid = threadIdx.x;
    const int lane = tid & 63, wv = tid >> 6;
    const int r16 = lane & 15, quad = lane >> 4;
    const int wr = wv >> 1, wc = wv & 1;     // wave tile in 2x2 grid

    // XCD-aware bijective swizzle
    int bid;
    if (bid0 < GT2_BLOCKS) bid = (bid0 & 7) * 16 + (bid0 >> 3);
    else { const int d = bid0 - GT2_BLOCKS; bid = GT2_BLOCKS + (d & 7) * 25 + (d >> 3); }

    const unsigned short *xh, *xl, *wh, *wl; const float* bias; float* Y;
    int ktiles, mt0, n8;
    if (bid < GT2_BLOCKS) {
        xh = Xh; xl = Xl; wh = WTh; wl = WTl; bias = bt; Y = pt; ktiles = KT_T;
        mt0 = (bid >> 3) * 4; n8 = bid & 7;
    } else {
        const int ib = bid - GT2_BLOCKS;
        xh = Xh + XT_ELEMS; xl = Xl + XT_ELEMS;
        wh = WTh + WT_T_ELEMS; wl = WTl + WT_T_ELEMS;
        bias = bi; Y = pi; ktiles = KT_I;
        const int mg = ib >> 3;
        mt0 = (mg == 24) ? (MT_I - 4) : mg * 4;   // tail overlaps (bit-identical)
        n8 = ib & 7;
    }
    const int nt0 = n8 * 4;

    const unsigned short* ssrc[4];
    #pragma unroll
    for (int q = 0; q < 4; ++q) {
        const int t = wv * 4 + q;
        const int g = t >> 2;            // 0:Ah 1:Al 2:Bh 3:Bl
        const int i = t & 3;
        const unsigned short* base = (g == 0) ? xh : (g == 1) ? xl : (g == 2) ? wh : wl;
        const long row = (g < 2) ? (long)(mt0 + i) : (long)(nt0 + i);
        ssrc[q] = base + row * ktiles * 512 + lane * 8;
    }

#define STAGE(buf, kt) do {                                                    \
        _Pragma("unroll")                                                      \
        for (int q_ = 0; q_ < 4; ++q_) {                                       \
            __builtin_amdgcn_global_load_lds(                                  \
                (as1_cvoid*)(ssrc[q_] + (long)(kt) * 512),                     \
                (as3_void*)&lds[buf][wv * 4 + q_][0], 16, 0, 0);               \
        } } while (0)

    f32x4 a00 = {0,0,0,0}, a01 = {0,0,0,0}, a10 = {0,0,0,0}, a11 = {0,0,0,0};

    STAGE(0, 0);
    __syncthreads();

    int cur = 0;
    for (int s = 0; s < ktiles; ++s) {
        if (s + 1 < ktiles) STAGE(cur ^ 1, s + 1);

        const int fo = lane * 8;
        const bf16x8 Ah0 = *(const bf16x8*)&lds[cur][wr * 2 + 0][fo];
        const bf16x8 Ah1 = *(const bf16x8*)&lds[cur][wr * 2 + 1][fo];
        const bf16x8 Al0 = *(const bf16x8*)&lds[cur][4 + wr * 2 + 0][fo];
        const bf16x8 Al1 = *(const bf16x8*)&lds[cur][4 + wr * 2 + 1][fo];
        const bf16x8 Bh0 = *(const bf16x8*)&lds[cur][8 + wc * 2 + 0][fo];
        const bf16x8 Bh1 = *(const bf16x8*)&lds[cur][8 + wc * 2 + 1][fo];
        const bf16x8 Bl0 = *(const bf16x8*)&lds[cur][12 + wc * 2 + 0][fo];
        const bf16x8 Bl1 = *(const bf16x8*)&lds[cur][12 + wc * 2 + 1][fo];

        a00 = __builtin_amdgcn_mfma_f32_16x16x32_bf16(Ah0, Bh0, a00, 0, 0, 0);
        a01 = __builtin_amdgcn_mfma_f32_16x16x32_bf16(Ah0, Bh1, a01, 0, 0, 0);
        a10 = __builtin_amdgcn_mfma_f32_16x16x32_bf16(Ah1, Bh0, a10, 0, 0, 0);
        a11 = __builtin_amdgcn_mfma_f32_16x16x32_bf16(Ah1, Bh1, a11, 0, 0, 0);
        a00 = __builtin_amdgcn_mfma_f32_16x16x32_bf16(Ah0, Bl0, a00, 0, 0, 0);
        a01 = __builtin_amdgcn_mfma_f32_16x16x32_bf16(Ah0, Bl1, a01, 0, 0, 0);
        a10 = __builtin_amdgcn_mfma_f32_16x16x32_bf16(Ah1, Bl0, a10, 0, 0, 0);
        a11 = __builtin_amdgcn_mfma_f32_16x16x32_bf16(Ah1, Bl1, a11, 0, 0, 0);
        a00 = __builtin_amdgcn_mfma_f32_16x16x32_bf16(Al0, Bh0, a00, 0, 0, 0);
        a01 = __builtin_amdgcn_mfma_f32_16x16x32_bf16(Al0, Bh1, a01, 0, 0, 0);
        a10 = __builtin_amdgcn_mfma_f32_16x16x32_bf16(Al1, Bh0, a10, 0, 0, 0);
        a11 = __builtin_amdgcn_mfma_f32_16x16x32_bf16(Al1, Bh1, a11, 0, 0, 0);

        __syncthreads();
        cur ^= 1;
    }
#undef STAGE

    const int row00 = (mt0 + wr * 2) * 16 + quad * 4;
    const int col0  = (nt0 + wc * 2) * 16 + r16;
    const float bv0 = bias[col0];
    const float bv1 = bias[col0 + 16];
    #pragma unroll
    for (int r = 0; r < 4; ++r) {
        Y[(long)(row00 + r)      * HIDDEN + col0]      = FAST_EXP2((a00[r] + bv0) * EXP_SCALE);
        Y[(long)(row00 + r)      * HIDDEN + col0 + 16] = FAST_EXP2((a01[r] + bv1) * EXP_SCALE);
        Y[(long)(row00 + 16 + r) * HIDDEN + col0]      = FAST_EXP2((a10[r] + bv0) * EXP_SCALE);
        Y[(long)(row00 + 16 + r) * HIDDEN + col0 + 16] = FAST_EXP2((a11[r] + bv1) * EXP_SCALE);
    }
}

// ---------------- phase C: scores (TM=2 t-rows per logical block) ----------
__device__ __forceinline__ void scores_block(const int blk,
        const float* __restrict__ pt, const float* __restrict__ pi,
        const float* __restrict__ wa, const float* __restrict__ ba,
        float* __restrict__ scores)
{
    const int half = blk & 1;
    const int bt0 = (blk >> 1) * 2;          // even text-row index
    const int b = bt0 >> 7;                  // /T
    const int tid = threadIdx.x;
    const int lane = tid & 63, wave = tid >> 6;

    const float* ptrow = pt + (long)bt0 * HIDDEN + lane * 8;
    const float4 pA0 = *(const float4*)ptrow;
    const float4 pB0 = *(const float4*)(ptrow + 4);
    const float4 pA1 = *(const float4*)(ptrow + HIDDEN);
    const float4 pB1 = *(const float4*)(ptrow + HIDDEN + 4);
    float4 wA = *(const float4*)(wa + lane * 8);
    float4 wB = *(const float4*)(wa + lane * 8 + 4);

    float S = wA.x + wA.y + wA.z + wA.w + wB.x + wB.y + wB.z + wB.w;
    #pragma unroll
    for (int off = 32; off; off >>= 1) S += __shfl_down(S, off);
    const float base = S + ba[0];

    wA.x *= -2.f; wA.y *= -2.f; wA.z *= -2.f; wA.w *= -2.f;
    wB.x *= -2.f; wB.y *= -2.f; wB.z *= -2.f; wB.w *= -2.f;

    const float* pib = pi + (long)b * I_TOK * HIDDEN + lane * 8;
    const int i0 = half * 98 + wave;
    const int iend = half * 98 + 98;

    float4 ca = *(const float4*)(pib + (long)i0 * HIDDEN);
    float4 cb = *(const float4*)(pib + (long)i0 * HIDDEN + 4);

    for (int i = i0; i < iend; i += 4) {
        const int inx = (i + 4 < iend) ? (i + 4) : i;
        const float4 na = *(const float4*)(pib + (long)inx * HIDDEN);
        const float4 nb = *(const float4*)(pib + (long)inx * HIDDEN + 4);

        float acc0 = 0.f;
        acc0 = fmaf(wA.x, FAST_RCP(fmaf(pA0.x, ca.x, 1.f)), acc0);
        acc0 = fmaf(wA.y, FAST_RCP(fmaf(pA0.y, ca.y, 1.f)), acc0);
        acc0 = fmaf(wA.z, FAST_RCP(fmaf(pA0.z, ca.z, 1.f)), acc0);
        acc0 = fmaf(wA.w, FAST_RCP(fmaf(pA0.w, ca.w, 1.f)), acc0);
        acc0 = fmaf(wB.x, FAST_RCP(fmaf(pB0.x, cb.x, 1.f)), acc0);
        acc0 = fmaf(wB.y, FAST_RCP(fmaf(pB0.y, cb.y, 1.f)), acc0);
        acc0 = fmaf(wB.z, FAST_RCP(fmaf(pB0.z, cb.z, 1.f)), acc0);
        acc0 = fmaf(wB.w, FAST_RCP(fmaf(pB0.w, cb.w, 1.f)), acc0);

        float acc1 = 0.f;
        acc1 = fmaf(wA.x, FAST_RCP(fmaf(pA1.x, ca.x, 1.f)), acc1);
        acc1 = fmaf(wA.y, FAST_RCP(fmaf(pA1.y, ca.y, 1.f)), acc1);
        acc1 = fmaf(wA.z, FAST_RCP(fmaf(pA1.z, ca.z, 1.f)), acc1);
        acc1 = fmaf(wA.w, FAST_RCP(fmaf(pA1.w, ca.w, 1.f)), acc1);
        acc1 = fmaf(wB.x, FAST_RCP(fmaf(pB1.x, cb.x, 1.f)), acc1);
        acc1 = fmaf(wB.y, FAST_RCP(fmaf(pB1.y, cb.y, 1.f)), acc1);
        acc1 = fmaf(wB.z, FAST_RCP(fmaf(pB1.z, cb.z, 1.f)), acc1);
        acc1 = fmaf(wB.w, FAST_RCP(fmaf(pB1.w, cb.w, 1.f)), acc1);

        #pragma unroll
        for (int off = 32; off; off >>= 1) {
            acc0 += __shfl_down(acc0, off);
            acc1 += __shfl_down(acc1, off);
        }
        if (lane == 0) {
            scores[(long)bt0 * I_TOK + i]       = base + acc0;
            scores[(long)(bt0 + 1) * I_TOK + i] = base + acc1;
        }
        ca = na; cb = nb;
    }
}

// ---------------- phase D: fused attended outputs --------------------------
__device__ __forceinline__ void att_block(const int bid0, unsigned char* smem,
        const float* __restrict__ scores,
        const float* __restrict__ image, const float* __restrict__ text,
        float* __restrict__ out_text, float* __restrict__ out_img)
{
    const int tid = threadIdx.x, lane = tid & 63, wave = tid >> 6;

    if (bid0 < ATT_P1_BLOCKS) {
        const int bid = bid0;
        const int csplit = bid & 1;
        const int grp = bid >> 1;            // 0..127
        const int b = grp >> 4;
        const int t0 = (grp & 15) * 8;

        float (*ps)[8] = (float (*)[8])smem;   // [I_TOK][8] = 6272 B
        #pragma unroll
        for (int rr = 0; rr < 2; ++rr) {
            const int tsub = wave + rr * 4;
            const float* srow = scores + ((long)(b * T + t0 + tsub)) * I_TOK;
            const float s0 = srow[lane];
            const float s1 = srow[lane + 64];
            const float s2 = srow[lane + 128];
            const float s3 = (lane < 4) ? srow[lane + 192] : -INFINITY;
            float m = fmaxf(fmaxf(s0, s1), fmaxf(s2, s3));
            #pragma unroll
            for (int off = 32; off; off >>= 1) m = fmaxf(m, __shfl_xor(m, off));
            const float e0 = __expf(s0 - m);
            const float e1 = __expf(s1 - m);
            const float e2 = __expf(s2 - m);
            const float e3 = (lane < 4) ? __expf(s3 - m) : 0.f;
            float sum = e0 + e1 + e2 + e3;
            #pragma unroll
            for (int off = 32; off; off >>= 1) sum += __shfl_xor(sum, off);
            const float inv = __fdividef(1.0f, sum);
            ps[lane][tsub] = e0 * inv;
            ps[lane + 64][tsub] = e1 * inv;
            ps[lane + 128][tsub] = e2 * inv;
            if (lane < 4) ps[lane + 192][tsub] = e3 * inv;
        }
        __syncthreads();

        const float* img = image + (long)b * I_TOK * IMAGE_DIM + csplit * 512 + tid * 2;
        float2 a0 = {0,0}, a1 = {0,0}, a2 = {0,0}, a3 = {0,0};
        float2 a4 = {0,0}, a5 = {0,0}, a6 = {0,0}, a7 = {0,0};

        float2 v0 = *(const float2*)(img + 0 * IMAGE_DIM);
        float2 v1 = *(const float2*)(img + 1 * IMAGE_DIM);
        float2 v2 = *(const float2*)(img + 2 * IMAGE_DIM);
        float2 v3 = *(const float2*)(img + 3 * IMAGE_DIM);
        float4 pL0 = *(const float4*)&ps[0][0]; float4 pH0 = *(const float4*)&ps[0][4];
        float4 pL1 = *(const float4*)&ps[1][0]; float4 pH1 = *(const float4*)&ps[1][4];
        float4 pL2 = *(const float4*)&ps[2][0]; float4 pH2 = *(const float4*)&ps[2][4];
        float4 pL3 = *(const float4*)&ps[3][0]; float4 pH3 = *(const float4*)&ps[3][4];

        for (int g = 0; g < 49; ++g) {
            const int ib = (g + 1 < 49) ? (g + 1) * 4 : g * 4;
            const float2 w0 = *(const float2*)(img + (long)(ib + 0) * IMAGE_DIM);
            const float2 w1 = *(const float2*)(img + (long)(ib + 1) * IMAGE_DIM);
            const float2 w2 = *(const float2*)(img + (long)(ib + 2) * IMAGE_DIM);
            const float2 w3 = *(const float2*)(img + (long)(ib + 3) * IMAGE_DIM);
            const float4 nL0 = *(const float4*)&ps[ib + 0][0]; const float4 nH0 = *(const float4*)&ps[ib + 0][4];
            const float4 nL1 = *(const float4*)&ps[ib + 1][0]; const float4 nH1 = *(const float4*)&ps[ib + 1][4];
            const float4 nL2 = *(const float4*)&ps[ib + 2][0]; const float4 nH2 = *(const float4*)&ps[ib + 2][4];
            const float4 nL3 = *(const float4*)&ps[ib + 3][0]; const float4 nH3 = *(const float4*)&ps[ib + 3][4];

#define ATT_ROW(vr, pl, ph)                                                   \
            a0.x = fmaf(pl.x, vr.x, a0.x); a0.y = fmaf(pl.x, vr.y, a0.y);     \
            a1.x = fmaf(pl.y, vr.x, a1.x); a1.y = fmaf(pl.y, vr.y, a1.y);     \
            a2.x = fmaf(pl.z, vr.x, a2.x); a2.y = fmaf(pl.z, vr.y, a2.y);     \
            a3.x = fmaf(pl.w, vr.x, a3.x); a3.y = fmaf(pl.w, vr.y, a3.y);     \
            a4.x = fmaf(ph.x, vr.x, a4.x); a4.y = fmaf(ph.x, vr.y, a4.y);     \
            a5.x = fmaf(ph.y, vr.x, a5.x); a5.y = fmaf(ph.y, vr.y, a5.y);     \
            a6.x = fmaf(ph.z, vr.x, a6.x); a6.y = fmaf(ph.z, vr.y, a6.y);     \
            a7.x = fmaf(ph.w, vr.x, a7.x); a7.y = fmaf(ph.w, vr.y, a7.y);
            ATT_ROW(v0, pL0, pH0)
            ATT_ROW(v1, pL1, pH1)
            ATT_ROW(v2, pL2, pH2)
            ATT_ROW(v3, pL3, pH3)
#undef ATT_ROW
            v0 = w0; v1 = w1; v2 = w2; v3 = w3;
            pL0 = nL0; pH0 = nH0; pL1 = nL1; pH1 = nH1;
            pL2 = nL2; pH2 = nH2; pL3 = nL3; pH3 = nH3;
        }
        float* o = out_text + ((long)(b * T + t0)) * IMAGE_DIM + csplit * 512 + tid * 2;
        *(float2*)(o + 0 * IMAGE_DIM) = a0;
        *(float2*)(o + 1 * IMAGE_DIM) = a1;
        *(float2*)(o + 2 * IMAGE_DIM) = a2;
        *(float2*)(o + 3 * IMAGE_DIM) = a3;
        *(float2*)(o + 4 * IMAGE_DIM) = a4;
        *(float2*)(o + 5 * IMAGE_DIM) = a5;
        *(float2*)(o + 6 * IMAGE_DIM) = a6;
        *(float2*)(o + 7 * IMAGE_DIM) = a7;
    } else {
        const int bid = bid0 - ATT_P1_BLOCKS;
        const int b = bid / 28;
        const int i0 = (bid % 28) * 7;

        float (*qs)[8] = (float (*)[8])smem;   // [T][8] = 4096 B, col 7 pad
        for (int cc = wave; cc < 7; cc += 4) {
            const float* sc = scores + (long)b * T * I_TOK + (i0 + cc);
            const float s0 = sc[(long)lane * I_TOK];
            const float s1 = sc[(long)(lane + 64) * I_TOK];
            float m = fmaxf(s0, s1);
            #pragma unroll
            for (int off = 32; off; off >>= 1) m = fmaxf(m, __shfl_xor(m, off));
            const float e0 = __expf(s0 - m);
            const float e1 = __expf(s1 - m);
            float sum = e0 + e1;
            #pragma unroll
            for (int off = 32; off; off >>= 1) sum += __shfl_xor(sum, off);
            const float inv = __fdividef(1.0f, sum);
            qs[lane][cc] = e0 * inv;
            qs[lane + 64][cc] = e1 * inv;
        }
        __syncthreads();

        const float* txt2 = text + (long)b * T * TEXT_DIM + tid * 2;
        const float* txt1 = text + (long)b * T * TEXT_DIM + 512 + tid;
        float ax[7], ay[7], az[7];
        #pragma unroll
        for (int r = 0; r < 7; ++r) { ax[r] = 0.f; ay[r] = 0.f; az[r] = 0.f; }

        float2 u0 = *(const float2*)(txt2 + 0 * TEXT_DIM);
        float2 u1 = *(const float2*)(txt2 + 1 * TEXT_DIM);
        float  z0 = txt1[0 * TEXT_DIM];
        float  z1 = txt1[1 * TEXT_DIM];
        float4 qa0 = *(const float4*)&qs[0][0]; float4 qb0 = *(const float4*)&qs[0][4];
        float4 qa1 = *(const float4*)&qs[1][0]; float4 qb1 = *(const float4*)&qs[1][4];

        for (int g = 0; g < 64; ++g) {
            const int tb = (g + 1 < 64) ? (g + 1) * 2 : g * 2;
            const float2 nu0 = *(const float2*)(txt2 + (long)(tb + 0) * TEXT_DIM);
            const float2 nu1 = *(const float2*)(txt2 + (long)(tb + 1) * TEXT_DIM);
            const float  nz0 = txt1[(long)(tb + 0) * TEXT_DIM];
            const float  nz1 = txt1[(long)(tb + 1) * TEXT_DIM];
            const float4 na0 = *(const float4*)&qs[tb + 0][0];
            const float4 nb0 = *(const float4*)&qs[tb + 0][4];
            const float4 na1 = *(const float4*)&qs[tb + 1][0];
            const float4 nb1 = *(const float4*)&qs[tb + 1][4];

            // row 2g
            ax[0] = fmaf(qa0.x, u0.x, ax[0]); ay[0] = fmaf(qa0.x, u0.y, ay[0]); az[0] = fmaf(qa0.x, z0, az[0]);
            ax[1] = fmaf(qa0.y, u0.x, ax[1]); ay[1] = fmaf(qa0.y, u0.y, ay[1]); az[1] = fmaf(qa0.y, z0, az[1]);
            ax[2] = fmaf(qa0.z, u0.x, ax[2]); ay[2] = fmaf(qa0.z, u0.y, ay[2]); az[2] = fmaf(qa0.z, z0, az[2]);
            ax[3] = fmaf(qa0.w, u0.x, ax[3]); ay[3] = fmaf(qa0.w, u0.y, ay[3]); az[3] = fmaf(qa0.w, z0, az[3]);
            ax[4] = fmaf(qb0.x, u0.x, ax[4]); ay[4] = fmaf(qb0.x, u0.y, ay[4]); az[4] = fmaf(qb0.x, z0, az[4]);
            ax[5] = fmaf(qb0.y, u0.x, ax[5]); ay[5] = fmaf(qb0.y, u0.y, ay[5]); az[5] = fmaf(qb0.y, z0, az[5]);
            ax[6] = fmaf(qb0.z, u0.x, ax[6]); ay[6] = fmaf(qb0.z, u0.y, ay[6]); az[6] = fmaf(qb0.z, z0, az[6]);
            // row 2g+1
            ax[0] = fmaf(qa1.x, u1.x, ax[0]); ay[0] = fmaf(qa1.x, u1.y, ay[0]); az[0] = fmaf(qa1.x, z1, az[0]);
            ax[1] = fmaf(qa1.y, u1.x, ax[1]); ay[1] = fmaf(qa1.y, u1.y, ay[1]); az[1] = fmaf(qa1.y, z1, az[1]);
            ax[2] = fmaf(qa1.z, u1.x, ax[2]); ay[2] = fmaf(qa1.z, u1.y, ay[2]); az[2] = fmaf(qa1.z, z1, az[2]);
            ax[3] = fmaf(qa1.w, u1.x, ax[3]); ay[3] = fmaf(qa1.w, u1.y, ay[3]); az[3] = fmaf(qa1.w, z1, az[3]);
            ax[4] = fmaf(qb1.x, u1.x, ax[4]); ay[4] = fmaf(qb1.x, u1.y, ay[4]); az[4] = fmaf(qb1.x, z1, az[4]);
            ax[5] = fmaf(qb1.y, u1.x, ax[5]); ay[5] = fmaf(qb1.y, u1.y, ay[5]); az[5] = fmaf(qb1.y, z1, az[5]);
            ax[6] = fmaf(qb1.z, u1.x, ax[6]); ay[6] = fmaf(qb1.z, u1.y, ay[6]); az[6] = fmaf(qb1.z, z1, az[6]);

            u0 = nu0; u1 = nu1; z0 = nz0; z1 = nz1;
            qa0 = na0; qb0 = nb0; qa1 = na1; qb1 = nb1;
        }
        float* o = out_img + ((long)b * I_TOK + i0) * TEXT_DIM;
        #pragma unroll
        for (int r = 0; r < 7; ++r) {
            float2 w;
            w.x = ax[r]; w.y = ay[r];
            *(float2*)(o + (long)r * TEXT_DIM + tid * 2) = w;
            o[(long)r * TEXT_DIM + 512 + tid] = az[r];
        }
    }
}

// ---------------- mega kernel: all 4 phases, 1 dispatch --------------------
__global__ __launch_bounds__(256, 2) void mega_kernel(
        const float* __restrict__ text, const float* __restrict__ image,
        const float* __restrict__ Wt, const float* __restrict__ bt,
        const float* __restrict__ Wi, const float* __restrict__ bi,
        const float* __restrict__ wa, const float* __restrict__ ba,
        unsigned short* __restrict__ Xh, unsigned short* __restrict__ Xl,
        unsigned short* __restrict__ WTh, unsigned short* __restrict__ WTl,
        float* __restrict__ pt, float* __restrict__ pi, float* __restrict__ sc,
        float* __restrict__ out_text, float* __restrict__ out_img,
        unsigned int* __restrict__ bar)
{
    __shared__ __align__(16) unsigned char smem[32768];
    const int wv = threadIdx.x >> 6;

    // phase A: prep (grid-stride, 4 tiles/block/iter)
    for (int base = 0; base < ALL_TILES; base += MEGA_GRID * 4) {
        const int id = base + blockIdx.x * 4 + wv;
        if (id < ALL_TILES) prep_tile(id, text, image, Wt, Wi, Xh, Xl, WTh, WTl);
    }
    grid_barrier(bar, 0);

    // phase B: projections
    if (blockIdx.x < GEMM_GRID)
        proj_block(blockIdx.x, (unsigned short (*)[16][512])smem,
                   Xh, Xl, WTh, WTl, bt, bi, pt, pi);
    grid_barrier(bar, 1);

    // phase C: scores (2 logical blocks each; pair shares pt rows + Ei base)
    scores_block(blockIdx.x * 2 + 0, pt, pi, wa, ba, sc);
    scores_block(blockIdx.x * 2 + 1, pt, pi, wa, ba, sc);
    grid_barrier(bar, 2);

    // phase D: attended outputs
    if (blockIdx.x < ATT_GRID)
        att_block(blockIdx.x, smem, sc, image, text, out_text, out_img);
}

extern "C" void kernel_launch(void* const* d_in, const int* in_sizes, int n_in,
                              void* d_out, int out_size, void* d_ws, size_t ws_size,
                              hipStream_t stream) {
    const float* text  = (const float*)d_in[0];
    const float* image = (const float*)d_in[1];
    const float* Wt    = (const float*)d_in[2];
    const float* bt    = (const float*)d_in[3];
    const float* Wi    = (const float*)d_in[4];
    const float* bi    = (const float*)d_in[5];
    const float* wa    = (const float*)d_in[6];
    const float* ba    = (const float*)d_in[7];

    float* pt = (float*)d_ws;                       // Et = exp2-transformed
    float* pi = pt + (long)B * T * HIDDEN;          // Ei
    float* sc = pi + (long)B * I_TOK * HIDDEN;
    unsigned short* Xh  = (unsigned short*)(sc + (long)B * T * I_TOK);
    unsigned short* Xl  = Xh + X_ELEMS;
    unsigned short* WTh = Xl + X_ELEMS;
    unsigned short* WTl = WTh + W_ELEMS;
    unsigned int*   bar = (unsigned int*)(WTl + W_ELEMS);

    float* out_text = (float*)d_out;                        // B*T*IMAGE_DIM
    float* out_img  = out_text + (long)B * T * IMAGE_DIM;   // B*I*TEXT_DIM

    hipMemsetAsync(bar, 0, 64, stream);
    mega_kernel<<<MEGA_GRID, 256, 0, stream>>>(
        text, image, Wt, bt, Wi, bi, wa, ba,
        Xh, Xl, WTh, WTl, pt, pi, sc, out_text, out_img, bar);
}

// Round 5
// 139.848 us; speedup vs baseline: 2.5833x; 2.5833x over previous
//
#include <hip/hip_runtime.h>
#include <math.h>

#define B 8
#define T 128
#define I_TOK 196
#define TEXT_DIM 768
#define IMAGE_DIM 1024
#define HIDDEN 512
#define EXP_SCALE 2.88539008177792681f   // 2*log2(e): exp(2x) = 2^(EXP_SCALE*x)

#if __has_builtin(__builtin_amdgcn_exp2f)
#define FAST_EXP2(x) __builtin_amdgcn_exp2f(x)
#else
#define FAST_EXP2(x) exp2f(x)
#endif
#if __has_builtin(__builtin_amdgcn_rcpf)
#define FAST_RCP(x) __builtin_amdgcn_rcpf(x)
#else
#define FAST_RCP(x) __fdividef(1.f, (x))
#endif

typedef short bf16x8 __attribute__((ext_vector_type(8)));
typedef float f32x4 __attribute__((ext_vector_type(4)));

typedef __attribute__((address_space(3))) void       as3_void;
typedef __attribute__((address_space(1))) const void as1_cvoid;

// ---- fragment-tiled layout geometry ---------------------------------------
// All MFMA operands stored as 16x32 tiles, 512 bf16 = 1KB each; within a
// tile, lane (r16 + 16*quad) owns 8 contiguous bf16 at tile_base + lane*8:
// element (row=r16, k=quad*8+j). One tile = one contiguous 1KB wave
// transaction = one global_load_lds_dwordx4.
#define KT_T (TEXT_DIM / 32)     // 24 k-tiles (text)
#define KT_I (IMAGE_DIM / 32)    // 32 k-tiles (image)
#define MT_T (B * T / 16)        // 64 m-tiles (text rows)
#define MT_I (B * I_TOK / 16)    // 98 m-tiles (image rows)
#define NT   (HIDDEN / 16)       // 32 n-tiles (W columns)

#define XT_ELEMS (MT_T * KT_T * 512)       // 786432
#define XI_ELEMS (MT_I * KT_I * 512)       // 1605632
#define X_ELEMS  (XT_ELEMS + XI_ELEMS)
#define WT_T_ELEMS (NT * KT_T * 512)       // 393216
#define W_ELEMS (WT_T_ELEMS + NT * KT_I * 512)

#define XTILES_T (MT_T * KT_T)             // 1536
#define XTILES   (XTILES_T + MT_I * KT_I)  // 4672
#define WTILES_T (NT * KT_T)               // 768
#define WTILES   (WTILES_T + NT * KT_I)    // 1792
#define PREP_GRID ((XTILES + WTILES) / 4)  // 1616 blocks, 1 tile per wave

__device__ __forceinline__ unsigned short f2bf(float x) {
    unsigned int u = __float_as_uint(x);
    unsigned int r = u + 0x7FFFu + ((u >> 16) & 1u);   // RNE
    return (unsigned short)(r >> 16);
}
__device__ __forceinline__ float bf2f(unsigned short h) {
    return __uint_as_float(((unsigned int)h) << 16);
}

// ---------------- prep v9: split-bf16 + fragment-tiling (unchanged) --------
__global__ __launch_bounds__(256) void prep_kernel(
        const float* __restrict__ text, const float* __restrict__ image,
        const float* __restrict__ Wt, const float* __restrict__ Wi,
        unsigned short* __restrict__ Xh, unsigned short* __restrict__ Xl,
        unsigned short* __restrict__ WTh, unsigned short* __restrict__ WTl)
{
    const int tid = threadIdx.x;
    const int lane = tid & 63, wv = tid >> 6;
    const int r16 = lane & 15, quad = lane >> 4;
    const int id = blockIdx.x * 4 + wv;

    float v[8];
    unsigned short* oh;
    unsigned short* ol;
    long dst;

    if (id < XTILES) {
        const float* X; int K, mt, kt;
        if (id < XTILES_T) { X = text; K = TEXT_DIM; mt = id / KT_T; kt = id % KT_T; }
        else { const int i2 = id - XTILES_T; X = image; K = IMAGE_DIM; mt = i2 / KT_I; kt = i2 % KT_I; }
        const float* src = X + (long)(mt * 16 + r16) * K + kt * 32 + quad * 8;
        const float4 a = *(const float4*)src;
        const float4 b = *(const float4*)(src + 4);
        v[0]=a.x; v[1]=a.y; v[2]=a.z; v[3]=a.w; v[4]=b.x; v[5]=b.y; v[6]=b.z; v[7]=b.w;
        oh = (id < XTILES_T) ? Xh : Xh + XT_ELEMS;
        ol = (id < XTILES_T) ? Xl : Xl + XT_ELEMS;
        const long tile = (id < XTILES_T) ? id : (long)(id - XTILES_T);
        dst = tile * 512 + lane * 8;
    } else {
        const int idw = id - XTILES;
        const float* W; int K, nt, kt;
        if (idw < WTILES_T) { W = Wt; K = TEXT_DIM; nt = idw / KT_T; kt = idw % KT_T; }
        else { const int i2 = idw - WTILES_T; W = Wi; K = IMAGE_DIM; nt = i2 / KT_I; kt = i2 % KT_I; }
        const float* src = W + (long)(kt * 32 + quad * 8) * HIDDEN + nt * 16 + r16;
        #pragma unroll
        for (int j = 0; j < 8; ++j) v[j] = src[(long)j * HIDDEN];
        oh = (idw < WTILES_T) ? WTh : WTh + WT_T_ELEMS;
        ol = (idw < WTILES_T) ? WTl : WTl + WT_T_ELEMS;
        const long tile = (idw < WTILES_T) ? idw : (long)(idw - WTILES_T);
        dst = tile * 512 + lane * 8;
    }

    uint4 hv, lv;
    unsigned int hh[8], ll[8];
    #pragma unroll
    for (int j = 0; j < 8; ++j) {
        hh[j] = f2bf(v[j]);
        ll[j] = f2bf(v[j] - bf2f((unsigned short)hh[j]));
    }
    hv.x = hh[0] | (hh[1] << 16); hv.y = hh[2] | (hh[3] << 16);
    hv.z = hh[4] | (hh[5] << 16); hv.w = hh[6] | (hh[7] << 16);
    lv.x = ll[0] | (ll[1] << 16); lv.y = ll[2] | (ll[3] << 16);
    lv.z = ll[4] | (ll[5] << 16); lv.w = ll[6] | (ll[7] << 16);
    *(uint4*)(oh + dst) = hv;
    *(uint4*)(ol + dst) = lv;
}

// ---------------- MFMA projections v11: 3-buffer counted-vmcnt pipeline ----
// R4 lesson: the 2-buffer __syncthreads drains vmcnt(0) each K-step, exposing
// full L2/L3 latency of the just-issued next stage (~400 cyc x 32 steps).
// T3/T4 recipe: 3 LDS buffers, raw s_barrier, counted vmcnt(8) steady-state
// (2 stages in flight, 4 loads/stage/wave). MFMA order per accumulator
// unchanged -> bit-identical output.
#define GT2_BLOCKS (16 * 8)                  // 128 (text: 16 m-groups x 8 n)
#define GI2_BLOCKS (25 * 8)                  // 200 (image: 25 m-groups x 8 n)
#define GEMM_GRID (GT2_BLOCKS + GI2_BLOCKS)  // 328

__global__ __launch_bounds__(256, 2) void mfma_proj_kernel(
        const unsigned short* __restrict__ Xh, const unsigned short* __restrict__ Xl,
        const unsigned short* __restrict__ WTh, const unsigned short* __restrict__ WTl,
        const float* __restrict__ bt, const float* __restrict__ bi,
        float* __restrict__ pt, float* __restrict__ pi)
{
    // slots 0-3: Ah(mt0..mt0+3)  4-7: Al  8-11: Bh(nt0..nt0+3)  12-15: Bl
    __shared__ __align__(16) unsigned short lds[3][16][512];   // 48 KB

    const int tid = threadIdx.x;
    const int lane = tid & 63, wv = tid >> 6;
    const int r16 = lane & 15, quad = lane >> 4;
    const int wr = wv >> 1, wc = wv & 1;     // wave tile in 2x2 grid

    // XCD-aware bijective swizzle: round-robin dispatch -> contiguous chunks
    const int bid0 = blockIdx.x;
    int bid;
    if (bid0 < GT2_BLOCKS) bid = (bid0 & 7) * 16 + (bid0 >> 3);
    else { const int d = bid0 - GT2_BLOCKS; bid = GT2_BLOCKS + (d & 7) * 25 + (d >> 3); }

    const unsigned short *xh, *xl, *wh, *wl; const float* bias; float* Y;
    int ktiles, mt0, n8;
    if (bid < GT2_BLOCKS) {
        xh = Xh; xl = Xl; wh = WTh; wl = WTl; bias = bt; Y = pt; ktiles = KT_T;
        mt0 = (bid >> 3) * 4; n8 = bid & 7;
    } else {
        const int ib = bid - GT2_BLOCKS;
        xh = Xh + XT_ELEMS; xl = Xl + XT_ELEMS;
        wh = WTh + WT_T_ELEMS; wl = WTl + WT_T_ELEMS;
        bias = bi; Y = pi; ktiles = KT_I;
        const int mg = ib >> 3;
        mt0 = (mg == 24) ? (MT_I - 4) : mg * 4;   // tail overlaps (bit-identical)
        n8 = ib & 7;
    }
    const int nt0 = n8 * 4;

    const unsigned short* ssrc[4];
    #pragma unroll
    for (int q = 0; q < 4; ++q) {
        const int t = wv * 4 + q;
        const int g = t >> 2;            // 0:Ah 1:Al 2:Bh 3:Bl
        const int i = t & 3;
        const unsigned short* base = (g == 0) ? xh : (g == 1) ? xl : (g == 2) ? wh : wl;
        const long row = (g < 2) ? (long)(mt0 + i) : (long)(nt0 + i);
        ssrc[q] = base + row * ktiles * 512 + lane * 8;
    }

#define STAGE(buf, kt) do {                                                    \
        _Pragma("unroll")                                                      \
        for (int q_ = 0; q_ < 4; ++q_) {                                       \
            __builtin_amdgcn_global_load_lds(                                  \
                (as1_cvoid*)(ssrc[q_] + (long)(kt) * 512),                     \
                (as3_void*)&lds[buf][wv * 4 + q_][0], 16, 0, 0);               \
        } } while (0)

    f32x4 a00 = {0,0,0,0}, a01 = {0,0,0,0}, a10 = {0,0,0,0}, a11 = {0,0,0,0};

    // prologue: 3 stages in flight (ktiles is 24 or 32, always >= 3)
    STAGE(0, 0);
    STAGE(1, 1);
    STAGE(2, 2);

    for (int s = 0; s < ktiles; ++s) {
        // stage s complete; stages s+1, s+2 (4 loads each per wave) may fly
        if (s + 2 < ktiles)      asm volatile("s_waitcnt vmcnt(8)" ::: "memory");
        else if (s + 1 < ktiles) asm volatile("s_waitcnt vmcnt(4)" ::: "memory");
        else                     asm volatile("s_waitcnt vmcnt(0)" ::: "memory");
        __builtin_amdgcn_s_barrier();      // all waves' stage-s data visible

        const int cur = s % 3;
        const int fo = lane * 8;
        const bf16x8 Ah0 = *(const bf16x8*)&lds[cur][wr * 2 + 0][fo];
        const bf16x8 Ah1 = *(const bf16x8*)&lds[cur][wr * 2 + 1][fo];
        const bf16x8 Al0 = *(const bf16x8*)&lds[cur][4 + wr * 2 + 0][fo];
        const bf16x8 Al1 = *(const bf16x8*)&lds[cur][4 + wr * 2 + 1][fo];
        const bf16x8 Bh0 = *(const bf16x8*)&lds[cur][8 + wc * 2 + 0][fo];
        const bf16x8 Bh1 = *(const bf16x8*)&lds[cur][8 + wc * 2 + 1][fo];
        const bf16x8 Bl0 = *(const bf16x8*)&lds[cur][12 + wc * 2 + 0][fo];
        const bf16x8 Bl1 = *(const bf16x8*)&lds[cur][12 + wc * 2 + 1][fo];

        a00 = __builtin_amdgcn_mfma_f32_16x16x32_bf16(Ah0, Bh0, a00, 0, 0, 0);
        a01 = __builtin_amdgcn_mfma_f32_16x16x32_bf16(Ah0, Bh1, a01, 0, 0, 0);
        a10 = __builtin_amdgcn_mfma_f32_16x16x32_bf16(Ah1, Bh0, a10, 0, 0, 0);
        a11 = __builtin_amdgcn_mfma_f32_16x16x32_bf16(Ah1, Bh1, a11, 0, 0, 0);
        a00 = __builtin_amdgcn_mfma_f32_16x16x32_bf16(Ah0, Bl0, a00, 0, 0, 0);
        a01 = __builtin_amdgcn_mfma_f32_16x16x32_bf16(Ah0, Bl1, a01, 0, 0, 0);
        a10 = __builtin_amdgcn_mfma_f32_16x16x32_bf16(Ah1, Bl0, a10, 0, 0, 0);
        a11 = __builtin_amdgcn_mfma_f32_16x16x32_bf16(Ah1, Bl1, a11, 0, 0, 0);
        a00 = __builtin_amdgcn_mfma_f32_16x16x32_bf16(Al0, Bh0, a00, 0, 0, 0);
        a01 = __builtin_amdgcn_mfma_f32_16x16x32_bf16(Al0, Bh1, a01, 0, 0, 0);
        a10 = __builtin_amdgcn_mfma_f32_16x16x32_bf16(Al1, Bh0, a10, 0, 0, 0);
        a11 = __builtin_amdgcn_mfma_f32_16x16x32_bf16(Al1, Bh1, a11, 0, 0, 0);

        __builtin_amdgcn_s_barrier();      // all waves done reading buf cur
        if (s + 3 < ktiles) STAGE(cur, s + 3);
    }
#undef STAGE

    // epilogue: bias + exp2 + store (full-K accumulators)
    const int row00 = (mt0 + wr * 2) * 16 + quad * 4;
    const int col0  = (nt0 + wc * 2) * 16 + r16;
    const float bv0 = bias[col0];
    const float bv1 = bias[col0 + 16];
    #pragma unroll
    for (int r = 0; r < 4; ++r) {
        Y[(long)(row00 + r)      * HIDDEN + col0]      = FAST_EXP2((a00[r] + bv0) * EXP_SCALE);
        Y[(long)(row00 + r)      * HIDDEN + col0 + 16] = FAST_EXP2((a01[r] + bv1) * EXP_SCALE);
        Y[(long)(row00 + 16 + r) * HIDDEN + col0]      = FAST_EXP2((a10[r] + bv0) * EXP_SCALE);
        Y[(long)(row00 + 16 + r) * HIDDEN + col0 + 16] = FAST_EXP2((a11[r] + bv1) * EXP_SCALE);
    }
}

// ---------------- Scores v9: TM=2 t-rows per block (unchanged) -------------
__global__ __launch_bounds__(256, 4) void scores_kernel(const float* __restrict__ pt,
        const float* __restrict__ pi, const float* __restrict__ wa,
        const float* __restrict__ ba, float* __restrict__ scores)
{
    const int blk = blockIdx.x;              // 0..1023
    const int half = blk & 1;
    const int bt0 = (blk >> 1) * 2;          // even text-row index
    const int b = bt0 >> 7;                  // /T
    const int tid = threadIdx.x;
    const int lane = tid & 63, wave = tid >> 6;

    const float* ptrow = pt + (long)bt0 * HIDDEN + lane * 8;
    const float4 pA0 = *(const float4*)ptrow;
    const float4 pB0 = *(const float4*)(ptrow + 4);
    const float4 pA1 = *(const float4*)(ptrow + HIDDEN);
    const float4 pB1 = *(const float4*)(ptrow + HIDDEN + 4);
    float4 wA = *(const float4*)(wa + lane * 8);
    float4 wB = *(const float4*)(wa + lane * 8 + 4);

    float S = wA.x + wA.y + wA.z + wA.w + wB.x + wB.y + wB.z + wB.w;
    #pragma unroll
    for (int off = 32; off; off >>= 1) S += __shfl_down(S, off);
    const float base = S + ba[0];

    wA.x *= -2.f; wA.y *= -2.f; wA.z *= -2.f; wA.w *= -2.f;
    wB.x *= -2.f; wB.y *= -2.f; wB.z *= -2.f; wB.w *= -2.f;

    const float* pib = pi + (long)b * I_TOK * HIDDEN + lane * 8;
    const int i0 = half * 98 + wave;
    const int iend = half * 98 + 98;

    float4 ca = *(const float4*)(pib + (long)i0 * HIDDEN);
    float4 cb = *(const float4*)(pib + (long)i0 * HIDDEN + 4);

    for (int i = i0; i < iend; i += 4) {
        const int inx = (i + 4 < iend) ? (i + 4) : i;
        const float4 na = *(const float4*)(pib + (long)inx * HIDDEN);
        const float4 nb = *(const float4*)(pib + (long)inx * HIDDEN + 4);

        float acc0 = 0.f;
        acc0 = fmaf(wA.x, FAST_RCP(fmaf(pA0.x, ca.x, 1.f)), acc0);
        acc0 = fmaf(wA.y, FAST_RCP(fmaf(pA0.y, ca.y, 1.f)), acc0);
        acc0 = fmaf(wA.z, FAST_RCP(fmaf(pA0.z, ca.z, 1.f)), acc0);
        acc0 = fmaf(wA.w, FAST_RCP(fmaf(pA0.w, ca.w, 1.f)), acc0);
        acc0 = fmaf(wB.x, FAST_RCP(fmaf(pB0.x, cb.x, 1.f)), acc0);
        acc0 = fmaf(wB.y, FAST_RCP(fmaf(pB0.y, cb.y, 1.f)), acc0);
        acc0 = fmaf(wB.z, FAST_RCP(fmaf(pB0.z, cb.z, 1.f)), acc0);
        acc0 = fmaf(wB.w, FAST_RCP(fmaf(pB0.w, cb.w, 1.f)), acc0);

        float acc1 = 0.f;
        acc1 = fmaf(wA.x, FAST_RCP(fmaf(pA1.x, ca.x, 1.f)), acc1);
        acc1 = fmaf(wA.y, FAST_RCP(fmaf(pA1.y, ca.y, 1.f)), acc1);
        acc1 = fmaf(wA.z, FAST_RCP(fmaf(pA1.z, ca.z, 1.f)), acc1);
        acc1 = fmaf(wA.w, FAST_RCP(fmaf(pA1.w, ca.w, 1.f)), acc1);
        acc1 = fmaf(wB.x, FAST_RCP(fmaf(pB1.x, cb.x, 1.f)), acc1);
        acc1 = fmaf(wB.y, FAST_RCP(fmaf(pB1.y, cb.y, 1.f)), acc1);
        acc1 = fmaf(wB.z, FAST_RCP(fmaf(pB1.z, cb.z, 1.f)), acc1);
        acc1 = fmaf(wB.w, FAST_RCP(fmaf(pB1.w, cb.w, 1.f)), acc1);

        #pragma unroll
        for (int off = 32; off; off >>= 1) {
            acc0 += __shfl_down(acc0, off);
            acc1 += __shfl_down(acc1, off);
        }
        if (lane == 0) {
            scores[(long)bt0 * I_TOK + i]       = base + acc0;
            scores[(long)(bt0 + 1) * I_TOK + i] = base + acc1;
        }
        ca = na; cb = nb;
    }
}

// ---------------- Fused attended outputs v9 (unchanged) --------------------
#define ATT_P1_BLOCKS 256                    // 8b * 16 grp * 2 csplit
#define ATT_P2_BLOCKS (B * 28)               // 196 = 28 * 7
#define ATT_GRID (ATT_P1_BLOCKS + ATT_P2_BLOCKS)   // 480

__global__ __launch_bounds__(256) void att_kernel(const float* __restrict__ scores,
        const float* __restrict__ image, const float* __restrict__ text,
        float* __restrict__ out_text, float* __restrict__ out_img)
{
    const int tid = threadIdx.x, lane = tid & 63, wave = tid >> 6;

    if (blockIdx.x < ATT_P1_BLOCKS) {
        const int bid = blockIdx.x;
        const int csplit = bid & 1;
        const int grp = bid >> 1;            // 0..127
        const int b = grp >> 4;
        const int t0 = (grp & 15) * 8;

        __shared__ float ps[I_TOK][8];
        #pragma unroll
        for (int rr = 0; rr < 2; ++rr) {
            const int tsub = wave + rr * 4;
            const float* srow = scores + ((long)(b * T + t0 + tsub)) * I_TOK;
            const float s0 = srow[lane];
            const float s1 = srow[lane + 64];
            const float s2 = srow[lane + 128];
            const float s3 = (lane < 4) ? srow[lane + 192] : -INFINITY;
            float m = fmaxf(fmaxf(s0, s1), fmaxf(s2, s3));
            #pragma unroll
            for (int off = 32; off; off >>= 1) m = fmaxf(m, __shfl_xor(m, off));
            const float e0 = __expf(s0 - m);
            const float e1 = __expf(s1 - m);
            const float e2 = __expf(s2 - m);
            const float e3 = (lane < 4) ? __expf(s3 - m) : 0.f;
            float sum = e0 + e1 + e2 + e3;
            #pragma unroll
            for (int off = 32; off; off >>= 1) sum += __shfl_xor(sum, off);
            const float inv = __fdividef(1.0f, sum);
            ps[lane][tsub] = e0 * inv;
            ps[lane + 64][tsub] = e1 * inv;
            ps[lane + 128][tsub] = e2 * inv;
            if (lane < 4) ps[lane + 192][tsub] = e3 * inv;
        }
        __syncthreads();

        const float* img = image + (long)b * I_TOK * IMAGE_DIM + csplit * 512 + tid * 2;
        float2 a0 = {0,0}, a1 = {0,0}, a2 = {0,0}, a3 = {0,0};
        float2 a4 = {0,0}, a5 = {0,0}, a6 = {0,0}, a7 = {0,0};

        float2 v0 = *(const float2*)(img + 0 * IMAGE_DIM);
        float2 v1 = *(const float2*)(img + 1 * IMAGE_DIM);
        float2 v2 = *(const float2*)(img + 2 * IMAGE_DIM);
        float2 v3 = *(const float2*)(img + 3 * IMAGE_DIM);
        float4 pL0 = *(const float4*)&ps[0][0]; float4 pH0 = *(const float4*)&ps[0][4];
        float4 pL1 = *(const float4*)&ps[1][0]; float4 pH1 = *(const float4*)&ps[1][4];
        float4 pL2 = *(const float4*)&ps[2][0]; float4 pH2 = *(const float4*)&ps[2][4];
        float4 pL3 = *(const float4*)&ps[3][0]; float4 pH3 = *(const float4*)&ps[3][4];

        for (int g = 0; g < 49; ++g) {
            const int ib = (g + 1 < 49) ? (g + 1) * 4 : g * 4;
            const float2 w0 = *(const float2*)(img + (long)(ib + 0) * IMAGE_DIM);
            const float2 w1 = *(const float2*)(img + (long)(ib + 1) * IMAGE_DIM);
            const float2 w2 = *(const float2*)(img + (long)(ib + 2) * IMAGE_DIM);
            const float2 w3 = *(const float2*)(img + (long)(ib + 3) * IMAGE_DIM);
            const float4 nL0 = *(const float4*)&ps[ib + 0][0]; const float4 nH0 = *(const float4*)&ps[ib + 0][4];
            const float4 nL1 = *(const float4*)&ps[ib + 1][0]; const float4 nH1 = *(const float4*)&ps[ib + 1][4];
            const float4 nL2 = *(const float4*)&ps[ib + 2][0]; const float4 nH2 = *(const float4*)&ps[ib + 2][4];
            const float4 nL3 = *(const float4*)&ps[ib + 3][0]; const float4 nH3 = *(const float4*)&ps[ib + 3][4];

#define ATT_ROW(vr, pl, ph)                                                   \
            a0.x = fmaf(pl.x, vr.x, a0.x); a0.y = fmaf(pl.x, vr.y, a0.y);     \
            a1.x = fmaf(pl.y, vr.x, a1.x); a1.y = fmaf(pl.y, vr.y, a1.y);     \
            a2.x = fmaf(pl.z, vr.x, a2.x); a2.y = fmaf(pl.z, vr.y, a2.y);     \
            a3.x = fmaf(pl.w, vr.x, a3.x); a3.y = fmaf(pl.w, vr.y, a3.y);     \
            a4.x = fmaf(ph.x, vr.x, a4.x); a4.y = fmaf(ph.x, vr.y, a4.y);     \
            a5.x = fmaf(ph.y, vr.x, a5.x); a5.y = fmaf(ph.y, vr.y, a5.y);     \
            a6.x = fmaf(ph.z, vr.x, a6.x); a6.y = fmaf(ph.z, vr.y, a6.y);     \
            a7.x = fmaf(ph.w, vr.x, a7.x); a7.y = fmaf(ph.w, vr.y, a7.y);
            ATT_ROW(v0, pL0, pH0)
            ATT_ROW(v1, pL1, pH1)
            ATT_ROW(v2, pL2, pH2)
            ATT_ROW(v3, pL3, pH3)
#undef ATT_ROW
            v0 = w0; v1 = w1; v2 = w2; v3 = w3;
            pL0 = nL0; pH0 = nH0; pL1 = nL1; pH1 = nH1;
            pL2 = nL2; pH2 = nH2; pL3 = nL3; pH3 = nH3;
        }
        float* o = out_text + ((long)(b * T + t0)) * IMAGE_DIM + csplit * 512 + tid * 2;
        *(float2*)(o + 0 * IMAGE_DIM) = a0;
        *(float2*)(o + 1 * IMAGE_DIM) = a1;
        *(float2*)(o + 2 * IMAGE_DIM) = a2;
        *(float2*)(o + 3 * IMAGE_DIM) = a3;
        *(float2*)(o + 4 * IMAGE_DIM) = a4;
        *(float2*)(o + 5 * IMAGE_DIM) = a5;
        *(float2*)(o + 6 * IMAGE_DIM) = a6;
        *(float2*)(o + 7 * IMAGE_DIM) = a7;
    } else {
        const int bid = blockIdx.x - ATT_P1_BLOCKS;
        const int b = bid / 28;
        const int i0 = (bid % 28) * 7;

        __shared__ float qs[T][8];           // col 7 is padding
        for (int cc = wave; cc < 7; cc += 4) {
            const float* sc = scores + (long)b * T * I_TOK + (i0 + cc);
            const float s0 = sc[(long)lane * I_TOK];
            const float s1 = sc[(long)(lane + 64) * I_TOK];
            float m = fmaxf(s0, s1);
            #pragma unroll
            for (int off = 32; off; off >>= 1) m = fmaxf(m, __shfl_xor(m, off));
            const float e0 = __expf(s0 - m);
            const float e1 = __expf(s1 - m);
            float sum = e0 + e1;
            #pragma unroll
            for (int off = 32; off; off >>= 1) sum += __shfl_xor(sum, off);
            const float inv = __fdividef(1.0f, sum);
            qs[lane][cc] = e0 * inv;
            qs[lane + 64][cc] = e1 * inv;
        }
        __syncthreads();

        const float* txt2 = text + (long)b * T * TEXT_DIM + tid * 2;
        const float* txt1 = text + (long)b * T * TEXT_DIM + 512 + tid;
        float ax[7], ay[7], az[7];
        #pragma unroll
        for (int r = 0; r < 7; ++r) { ax[r] = 0.f; ay[r] = 0.f; az[r] = 0.f; }

        float2 u0 = *(const float2*)(txt2 + 0 * TEXT_DIM);
        float2 u1 = *(const float2*)(txt2 + 1 * TEXT_DIM);
        float  z0 = txt1[0 * TEXT_DIM];
        float  z1 = txt1[1 * TEXT_DIM];
        float4 qa0 = *(const float4*)&qs[0][0]; float4 qb0 = *(const float4*)&qs[0][4];
        float4 qa1 = *(const float4*)&qs[1][0]; float4 qb1 = *(const float4*)&qs[1][4];

        for (int g = 0; g < 64; ++g) {
            const int tb = (g + 1 < 64) ? (g + 1) * 2 : g * 2;
            const float2 nu0 = *(const float2*)(txt2 + (long)(tb + 0) * TEXT_DIM);
            const float2 nu1 = *(const float2*)(txt2 + (long)(tb + 1) * TEXT_DIM);
            const float  nz0 = txt1[(long)(tb + 0) * TEXT_DIM];
            const float  nz1 = txt1[(long)(tb + 1) * TEXT_DIM];
            const float4 na0 = *(const float4*)&qs[tb + 0][0];
            const float4 nb0 = *(const float4*)&qs[tb + 0][4];
            const float4 na1 = *(const float4*)&qs[tb + 1][0];
            const float4 nb1 = *(const float4*)&qs[tb + 1][4];

            // row 2g
            ax[0] = fmaf(qa0.x, u0.x, ax[0]); ay[0] = fmaf(qa0.x, u0.y, ay[0]); az[0] = fmaf(qa0.x, z0, az[0]);
            ax[1] = fmaf(qa0.y, u0.x, ax[1]); ay[1] = fmaf(qa0.y, u0.y, ay[1]); az[1] = fmaf(qa0.y, z0, az[1]);
            ax[2] = fmaf(qa0.z, u0.x, ax[2]); ay[2] = fmaf(qa0.z, u0.y, ay[2]); az[2] = fmaf(qa0.z, z0, az[2]);
            ax[3] = fmaf(qa0.w, u0.x, ax[3]); ay[3] = fmaf(qa0.w, u0.y, ay[3]); az[3] = fmaf(qa0.w, z0, az[3]);
            ax[4] = fmaf(qb0.x, u0.x, ax[4]); ay[4] = fmaf(qb0.x, u0.y, ay[4]); az[4] = fmaf(qb0.x, z0, az[4]);
            ax[5] = fmaf(qb0.y, u0.x, ax[5]); ay[5] = fmaf(qb0.y, u0.y, ay[5]); az[5] = fmaf(qb0.y, z0, az[5]);
            ax[6] = fmaf(qb0.z, u0.x, ax[6]); ay[6] = fmaf(qb0.z, u0.y, ay[6]); az[6] = fmaf(qb0.z, z0, az[6]);
            // row 2g+1
            ax[0] = fmaf(qa1.x, u1.x, ax[0]); ay[0] = fmaf(qa1.x, u1.y, ay[0]); az[0] = fmaf(qa1.x, z1, az[0]);
            ax[1] = fmaf(qa1.y, u1.x, ax[1]); ay[1] = fmaf(qa1.y, u1.y, ay[1]); az[1] = fmaf(qa1.y, z1, az[1]);
            ax[2] = fmaf(qa1.z, u1.x, ax[2]); ay[2] = fmaf(qa1.z, u1.y, ay[2]); az[2] = fmaf(qa1.z, z1, az[2]);
            ax[3] = fmaf(qa1.w, u1.x, ax[3]); ay[3] = fmaf(qa1.w, u1.y, ay[3]); az[3] = fmaf(qa1.w, z1, az[3]);
            ax[4] = fmaf(qb1.x, u1.x, ax[4]); ay[4] = fmaf(qb1.x, u1.y, ay[4]); az[4] = fmaf(qb1.x, z1, az[4]);
            ax[5] = fmaf(qb1.y, u1.x, ax[5]); ay[5] = fmaf(qb1.y, u1.y, ay[5]); az[5] = fmaf(qb1.y, z1, az[5]);
            ax[6] = fmaf(qb1.z, u1.x, ax[6]); ay[6] = fmaf(qb1.z, u1.y, ay[6]); az[6] = fmaf(qb1.z, z1, az[6]);

            u0 = nu0; u1 = nu1; z0 = nz0; z1 = nz1;
            qa0 = na0; qb0 = nb0; qa1 = na1; qb1 = nb1;
        }
        float* o = out_img + ((long)b * I_TOK + i0) * TEXT_DIM;
        #pragma unroll
        for (int r = 0; r < 7; ++r) {
            float2 w;
            w.x = ax[r]; w.y = ay[r];
            *(float2*)(o + (long)r * TEXT_DIM + tid * 2) = w;
            o[(long)r * TEXT_DIM + 512 + tid] = az[r];
        }
    }
}

extern "C" void kernel_launch(void* const* d_in, const int* in_sizes, int n_in,
                              void* d_out, int out_size, void* d_ws, size_t ws_size,
                              hipStream_t stream) {
    const float* text  = (const float*)d_in[0];
    const float* image = (const float*)d_in[1];
    const float* Wt    = (const float*)d_in[2];
    const float* bt    = (const float*)d_in[3];
    const float* Wi    = (const float*)d_in[4];
    const float* bi    = (const float*)d_in[5];
    const float* wa    = (const float*)d_in[6];
    const float* ba    = (const float*)d_in[7];

    float* pt = (float*)d_ws;                       // Et = exp2-transformed
    float* pi = pt + (long)B * T * HIDDEN;          // Ei
    float* sc = pi + (long)B * I_TOK * HIDDEN;
    unsigned short* Xh  = (unsigned short*)(sc + (long)B * T * I_TOK);
    unsigned short* Xl  = Xh + X_ELEMS;
    unsigned short* WTh = Xl + X_ELEMS;
    unsigned short* WTl = WTh + W_ELEMS;

    float* out_text = (float*)d_out;                        // B*T*IMAGE_DIM
    float* out_img  = out_text + (long)B * T * IMAGE_DIM;   // B*I*TEXT_DIM

    prep_kernel<<<PREP_GRID, 256, 0, stream>>>(text, image, Wt, Wi, Xh, Xl, WTh, WTl);
    mfma_proj_kernel<<<GEMM_GRID, 256, 0, stream>>>(Xh, Xl, WTh, WTl, bt, bi, pt, pi);
    scores_kernel<<<B * T, 256, 0, stream>>>(pt, pi, wa, ba, sc);
    att_kernel<<<ATT_GRID, 256, 0, stream>>>(sc, image, text, out_text, out_img);
}

// Round 6
// 137.140 us; speedup vs baseline: 2.6343x; 1.0197x over previous
//
#include <hip/hip_runtime.h>
#include <math.h>

#define B 8
#define T 128
#define I_TOK 196
#define TEXT_DIM 768
#define IMAGE_DIM 1024
#define HIDDEN 512
#define EXP_SCALE 2.88539008177792681f   // 2*log2(e): exp(2x) = 2^(EXP_SCALE*x)

#if __has_builtin(__builtin_amdgcn_exp2f)
#define FAST_EXP2(x) __builtin_amdgcn_exp2f(x)
#else
#define FAST_EXP2(x) exp2f(x)
#endif
#if __has_builtin(__builtin_amdgcn_rcpf)
#define FAST_RCP(x) __builtin_amdgcn_rcpf(x)
#else
#define FAST_RCP(x) __fdividef(1.f, (x))
#endif

typedef short bf16x8 __attribute__((ext_vector_type(8)));
typedef float f32x4 __attribute__((ext_vector_type(4)));

typedef __attribute__((address_space(3))) void       as3_void;
typedef __attribute__((address_space(1))) const void as1_cvoid;

// ---- fragment-tiled layout geometry ---------------------------------------
#define KT_T (TEXT_DIM / 32)     // 24 k-tiles (text)
#define KT_I (IMAGE_DIM / 32)    // 32 k-tiles (image)
#define MT_T (B * T / 16)        // 64 m-tiles (text rows)
#define MT_I (B * I_TOK / 16)    // 98 m-tiles (image rows)
#define NT   (HIDDEN / 16)       // 32 n-tiles (W columns)

#define XT_ELEMS (MT_T * KT_T * 512)       // 786432
#define XI_ELEMS (MT_I * KT_I * 512)       // 1605632
#define X_ELEMS  (XT_ELEMS + XI_ELEMS)
#define WT_T_ELEMS (NT * KT_T * 512)       // 393216
#define W_ELEMS (WT_T_ELEMS + NT * KT_I * 512)

#define XTILES_T (MT_T * KT_T)             // 1536
#define XTILES   (XTILES_T + MT_I * KT_I)  // 4672
#define WTILES_T (NT * KT_T)               // 768
#define WTILES   (WTILES_T + NT * KT_I)    // 1792
#define PREP_GRID ((XTILES + WTILES) / 4)  // 1616 blocks, 1 tile per wave

__device__ __forceinline__ unsigned short f2bf(float x) {
    unsigned int u = __float_as_uint(x);
    unsigned int r = u + 0x7FFFu + ((u >> 16) & 1u);   // RNE
    return (unsigned short)(r >> 16);
}
__device__ __forceinline__ float bf2f(unsigned short h) {
    return __uint_as_float(((unsigned int)h) << 16);
}

// ---------------- prep v9: split-bf16 + fragment-tiling (unchanged) --------
__global__ __launch_bounds__(256) void prep_kernel(
        const float* __restrict__ text, const float* __restrict__ image,
        const float* __restrict__ Wt, const float* __restrict__ Wi,
        unsigned short* __restrict__ Xh, unsigned short* __restrict__ Xl,
        unsigned short* __restrict__ WTh, unsigned short* __restrict__ WTl)
{
    const int tid = threadIdx.x;
    const int lane = tid & 63, wv = tid >> 6;
    const int r16 = lane & 15, quad = lane >> 4;
    const int id = blockIdx.x * 4 + wv;

    float v[8];
    unsigned short* oh;
    unsigned short* ol;
    long dst;

    if (id < XTILES) {
        const float* X; int K, mt, kt;
        if (id < XTILES_T) { X = text; K = TEXT_DIM; mt = id / KT_T; kt = id % KT_T; }
        else { const int i2 = id - XTILES_T; X = image; K = IMAGE_DIM; mt = i2 / KT_I; kt = i2 % KT_I; }
        const float* src = X + (long)(mt * 16 + r16) * K + kt * 32 + quad * 8;
        const float4 a = *(const float4*)src;
        const float4 b = *(const float4*)(src + 4);
        v[0]=a.x; v[1]=a.y; v[2]=a.z; v[3]=a.w; v[4]=b.x; v[5]=b.y; v[6]=b.z; v[7]=b.w;
        oh = (id < XTILES_T) ? Xh : Xh + XT_ELEMS;
        ol = (id < XTILES_T) ? Xl : Xl + XT_ELEMS;
        const long tile = (id < XTILES_T) ? id : (long)(id - XTILES_T);
        dst = tile * 512 + lane * 8;
    } else {
        const int idw = id - XTILES;
        const float* W; int K, nt, kt;
        if (idw < WTILES_T) { W = Wt; K = TEXT_DIM; nt = idw / KT_T; kt = idw % KT_T; }
        else { const int i2 = idw - WTILES_T; W = Wi; K = IMAGE_DIM; nt = i2 / KT_I; kt = i2 % KT_I; }
        const float* src = W + (long)(kt * 32 + quad * 8) * HIDDEN + nt * 16 + r16;
        #pragma unroll
        for (int j = 0; j < 8; ++j) v[j] = src[(long)j * HIDDEN];
        oh = (idw < WTILES_T) ? WTh : WTh + WT_T_ELEMS;
        ol = (idw < WTILES_T) ? WTl : WTl + WT_T_ELEMS;
        const long tile = (idw < WTILES_T) ? idw : (long)(idw - WTILES_T);
        dst = tile * 512 + lane * 8;
    }

    uint4 hv, lv;
    unsigned int hh[8], ll[8];
    #pragma unroll
    for (int j = 0; j < 8; ++j) {
        hh[j] = f2bf(v[j]);
        ll[j] = f2bf(v[j] - bf2f((unsigned short)hh[j]));
    }
    hv.x = hh[0] | (hh[1] << 16); hv.y = hh[2] | (hh[3] << 16);
    hv.z = hh[4] | (hh[5] << 16); hv.w = hh[6] | (hh[7] << 16);
    lv.x = ll[0] | (ll[1] << 16); lv.y = ll[2] | (ll[3] << 16);
    lv.z = ll[4] | (ll[5] << 16); lv.w = ll[6] | (ll[7] << 16);
    *(uint4*)(oh + dst) = hv;
    *(uint4*)(ol + dst) = lv;
}

// ---------------- MFMA projections v11 (unchanged from R5) -----------------
#define GT2_BLOCKS (16 * 8)                  // 128 (text: 16 m-groups x 8 n)
#define GI2_BLOCKS (25 * 8)                  // 200 (image: 25 m-groups x 8 n)
#define GEMM_GRID (GT2_BLOCKS + GI2_BLOCKS)  // 328

__global__ __launch_bounds__(256, 2) void mfma_proj_kernel(
        const unsigned short* __restrict__ Xh, const unsigned short* __restrict__ Xl,
        const unsigned short* __restrict__ WTh, const unsigned short* __restrict__ WTl,
        const float* __restrict__ bt, const float* __restrict__ bi,
        float* __restrict__ pt, float* __restrict__ pi)
{
    // slots 0-3: Ah(mt0..mt0+3)  4-7: Al  8-11: Bh(nt0..nt0+3)  12-15: Bl
    __shared__ __align__(16) unsigned short lds[3][16][512];   // 48 KB

    const int tid = threadIdx.x;
    const int lane = tid & 63, wv = tid >> 6;
    const int r16 = lane & 15, quad = lane >> 4;
    const int wr = wv >> 1, wc = wv & 1;     // wave tile in 2x2 grid

    // XCD-aware bijective swizzle
    const int bid0 = blockIdx.x;
    int bid;
    if (bid0 < GT2_BLOCKS) bid = (bid0 & 7) * 16 + (bid0 >> 3);
    else { const int d = bid0 - GT2_BLOCKS; bid = GT2_BLOCKS + (d & 7) * 25 + (d >> 3); }

    const unsigned short *xh, *xl, *wh, *wl; const float* bias; float* Y;
    int ktiles, mt0, n8;
    if (bid < GT2_BLOCKS) {
        xh = Xh; xl = Xl; wh = WTh; wl = WTl; bias = bt; Y = pt; ktiles = KT_T;
        mt0 = (bid >> 3) * 4; n8 = bid & 7;
    } else {
        const int ib = bid - GT2_BLOCKS;
        xh = Xh + XT_ELEMS; xl = Xl + XT_ELEMS;
        wh = WTh + WT_T_ELEMS; wl = WTl + WT_T_ELEMS;
        bias = bi; Y = pi; ktiles = KT_I;
        const int mg = ib >> 3;
        mt0 = (mg == 24) ? (MT_I - 4) : mg * 4;   // tail overlaps (bit-identical)
        n8 = ib & 7;
    }
    const int nt0 = n8 * 4;

    const unsigned short* ssrc[4];
    #pragma unroll
    for (int q = 0; q < 4; ++q) {
        const int t = wv * 4 + q;
        const int g = t >> 2;            // 0:Ah 1:Al 2:Bh 3:Bl
        const int i = t & 3;
        const unsigned short* base = (g == 0) ? xh : (g == 1) ? xl : (g == 2) ? wh : wl;
        const long row = (g < 2) ? (long)(mt0 + i) : (long)(nt0 + i);
        ssrc[q] = base + row * ktiles * 512 + lane * 8;
    }

#define STAGE(buf, kt) do {                                                    \
        _Pragma("unroll")                                                      \
        for (int q_ = 0; q_ < 4; ++q_) {                                       \
            __builtin_amdgcn_global_load_lds(                                  \
                (as1_cvoid*)(ssrc[q_] + (long)(kt) * 512),                     \
                (as3_void*)&lds[buf][wv * 4 + q_][0], 16, 0, 0);               \
        } } while (0)

    f32x4 a00 = {0,0,0,0}, a01 = {0,0,0,0}, a10 = {0,0,0,0}, a11 = {0,0,0,0};

    // prologue: 3 stages in flight (ktiles is 24 or 32, always >= 3)
    STAGE(0, 0);
    STAGE(1, 1);
    STAGE(2, 2);

    for (int s = 0; s < ktiles; ++s) {
        if (s + 2 < ktiles)      asm volatile("s_waitcnt vmcnt(8)" ::: "memory");
        else if (s + 1 < ktiles) asm volatile("s_waitcnt vmcnt(4)" ::: "memory");
        else                     asm volatile("s_waitcnt vmcnt(0)" ::: "memory");
        __builtin_amdgcn_s_barrier();      // all waves' stage-s data visible

        const int cur = s % 3;
        const int fo = lane * 8;
        const bf16x8 Ah0 = *(const bf16x8*)&lds[cur][wr * 2 + 0][fo];
        const bf16x8 Ah1 = *(const bf16x8*)&lds[cur][wr * 2 + 1][fo];
        const bf16x8 Al0 = *(const bf16x8*)&lds[cur][4 + wr * 2 + 0][fo];
        const bf16x8 Al1 = *(const bf16x8*)&lds[cur][4 + wr * 2 + 1][fo];
        const bf16x8 Bh0 = *(const bf16x8*)&lds[cur][8 + wc * 2 + 0][fo];
        const bf16x8 Bh1 = *(const bf16x8*)&lds[cur][8 + wc * 2 + 1][fo];
        const bf16x8 Bl0 = *(const bf16x8*)&lds[cur][12 + wc * 2 + 0][fo];
        const bf16x8 Bl1 = *(const bf16x8*)&lds[cur][12 + wc * 2 + 1][fo];

        a00 = __builtin_amdgcn_mfma_f32_16x16x32_bf16(Ah0, Bh0, a00, 0, 0, 0);
        a01 = __builtin_amdgcn_mfma_f32_16x16x32_bf16(Ah0, Bh1, a01, 0, 0, 0);
        a10 = __builtin_amdgcn_mfma_f32_16x16x32_bf16(Ah1, Bh0, a10, 0, 0, 0);
        a11 = __builtin_amdgcn_mfma_f32_16x16x32_bf16(Ah1, Bh1, a11, 0, 0, 0);
        a00 = __builtin_amdgcn_mfma_f32_16x16x32_bf16(Ah0, Bl0, a00, 0, 0, 0);
        a01 = __builtin_amdgcn_mfma_f32_16x16x32_bf16(Ah0, Bl1, a01, 0, 0, 0);
        a10 = __builtin_amdgcn_mfma_f32_16x16x32_bf16(Ah1, Bl0, a10, 0, 0, 0);
        a11 = __builtin_amdgcn_mfma_f32_16x16x32_bf16(Ah1, Bl1, a11, 0, 0, 0);
        a00 = __builtin_amdgcn_mfma_f32_16x16x32_bf16(Al0, Bh0, a00, 0, 0, 0);
        a01 = __builtin_amdgcn_mfma_f32_16x16x32_bf16(Al0, Bh1, a01, 0, 0, 0);
        a10 = __builtin_amdgcn_mfma_f32_16x16x32_bf16(Al1, Bh0, a10, 0, 0, 0);
        a11 = __builtin_amdgcn_mfma_f32_16x16x32_bf16(Al1, Bh1, a11, 0, 0, 0);

        __builtin_amdgcn_s_barrier();      // all waves done reading buf cur
        if (s + 3 < ktiles) STAGE(cur, s + 3);
    }
#undef STAGE

    const int row00 = (mt0 + wr * 2) * 16 + quad * 4;
    const int col0  = (nt0 + wc * 2) * 16 + r16;
    const float bv0 = bias[col0];
    const float bv1 = bias[col0 + 16];
    #pragma unroll
    for (int r = 0; r < 4; ++r) {
        Y[(long)(row00 + r)      * HIDDEN + col0]      = FAST_EXP2((a00[r] + bv0) * EXP_SCALE);
        Y[(long)(row00 + r)      * HIDDEN + col0 + 16] = FAST_EXP2((a01[r] + bv1) * EXP_SCALE);
        Y[(long)(row00 + 16 + r) * HIDDEN + col0]      = FAST_EXP2((a10[r] + bv0) * EXP_SCALE);
        Y[(long)(row00 + 16 + r) * HIDDEN + col0 + 16] = FAST_EXP2((a11[r] + bv1) * EXP_SCALE);
    }
}

// ---------------- Scores v10: 4-way i-chunks, 6 blocks/CU ------------------
// Latency/TLP fix (R5 post-mortem: bodies 2-3x above issue floors). Grid
// 2048 = 512 bt-pairs x 4 i-chunks of 49; launch_bounds(256,6) -> 6
// blocks/CU (24 waves). Each score still computed by ONE wave in ONE
// iteration with identical fma/rcp/shfl order -> bit-identical.
__global__ __launch_bounds__(256, 6) void scores_kernel(const float* __restrict__ pt,
        const float* __restrict__ pi, const float* __restrict__ wa,
        const float* __restrict__ ba, float* __restrict__ scores)
{
    const int blk = blockIdx.x;              // 0..2047
    const int chunk = blk & 3;
    const int bt0 = (blk >> 2) * 2;          // even text-row index
    const int b = bt0 >> 7;                  // /T
    const int tid = threadIdx.x;
    const int lane = tid & 63, wave = tid >> 6;

    const float* ptrow = pt + (long)bt0 * HIDDEN + lane * 8;
    const float4 pA0 = *(const float4*)ptrow;
    const float4 pB0 = *(const float4*)(ptrow + 4);
    const float4 pA1 = *(const float4*)(ptrow + HIDDEN);
    const float4 pB1 = *(const float4*)(ptrow + HIDDEN + 4);
    float4 wA = *(const float4*)(wa + lane * 8);
    float4 wB = *(const float4*)(wa + lane * 8 + 4);

    float S = wA.x + wA.y + wA.z + wA.w + wB.x + wB.y + wB.z + wB.w;
    #pragma unroll
    for (int off = 32; off; off >>= 1) S += __shfl_down(S, off);
    const float base = S + ba[0];

    wA.x *= -2.f; wA.y *= -2.f; wA.z *= -2.f; wA.w *= -2.f;
    wB.x *= -2.f; wB.y *= -2.f; wB.z *= -2.f; wB.w *= -2.f;

    const float* pib = pi + (long)b * I_TOK * HIDDEN + lane * 8;
    const int i0 = chunk * 49 + wave;
    const int iend = chunk * 49 + 49;

    float4 ca = *(const float4*)(pib + (long)i0 * HIDDEN);
    float4 cb = *(const float4*)(pib + (long)i0 * HIDDEN + 4);

    for (int i = i0; i < iend; i += 4) {
        const int inx = (i + 4 < iend) ? (i + 4) : i;
        const float4 na = *(const float4*)(pib + (long)inx * HIDDEN);
        const float4 nb = *(const float4*)(pib + (long)inx * HIDDEN + 4);

        float acc0 = 0.f;
        acc0 = fmaf(wA.x, FAST_RCP(fmaf(pA0.x, ca.x, 1.f)), acc0);
        acc0 = fmaf(wA.y, FAST_RCP(fmaf(pA0.y, ca.y, 1.f)), acc0);
        acc0 = fmaf(wA.z, FAST_RCP(fmaf(pA0.z, ca.z, 1.f)), acc0);
        acc0 = fmaf(wA.w, FAST_RCP(fmaf(pA0.w, ca.w, 1.f)), acc0);
        acc0 = fmaf(wB.x, FAST_RCP(fmaf(pB0.x, cb.x, 1.f)), acc0);
        acc0 = fmaf(wB.y, FAST_RCP(fmaf(pB0.y, cb.y, 1.f)), acc0);
        acc0 = fmaf(wB.z, FAST_RCP(fmaf(pB0.z, cb.z, 1.f)), acc0);
        acc0 = fmaf(wB.w, FAST_RCP(fmaf(pB0.w, cb.w, 1.f)), acc0);

        float acc1 = 0.f;
        acc1 = fmaf(wA.x, FAST_RCP(fmaf(pA1.x, ca.x, 1.f)), acc1);
        acc1 = fmaf(wA.y, FAST_RCP(fmaf(pA1.y, ca.y, 1.f)), acc1);
        acc1 = fmaf(wA.z, FAST_RCP(fmaf(pA1.z, ca.z, 1.f)), acc1);
        acc1 = fmaf(wA.w, FAST_RCP(fmaf(pA1.w, ca.w, 1.f)), acc1);
        acc1 = fmaf(wB.x, FAST_RCP(fmaf(pB1.x, cb.x, 1.f)), acc1);
        acc1 = fmaf(wB.y, FAST_RCP(fmaf(pB1.y, cb.y, 1.f)), acc1);
        acc1 = fmaf(wB.z, FAST_RCP(fmaf(pB1.z, cb.z, 1.f)), acc1);
        acc1 = fmaf(wB.w, FAST_RCP(fmaf(pB1.w, cb.w, 1.f)), acc1);

        #pragma unroll
        for (int off = 32; off; off >>= 1) {
            acc0 += __shfl_down(acc0, off);
            acc1 += __shfl_down(acc1, off);
        }
        if (lane == 0) {
            scores[(long)bt0 * I_TOK + i]       = base + acc0;
            scores[(long)(bt0 + 1) * I_TOK + i] = base + acc1;
        }
        ca = na; cb = nb;
    }
}

// ---------------- Fused attended outputs v10: 2-deep global prefetch -------
// Same tiling as v9; image/text row streams now 3-register-set (2 iterations
// ahead) so ~200-300cy L2 latency hides under the ~230cy FMA block at only
// ~2 blocks/CU. FMA order per output element unchanged.
#define ATT_P1_BLOCKS 256                    // 8b * 16 grp * 2 csplit
#define ATT_P2_BLOCKS (B * 28)               // 196 = 28 * 7
#define ATT_GRID (ATT_P1_BLOCKS + ATT_P2_BLOCKS)   // 480

__global__ __launch_bounds__(256) void att_kernel(const float* __restrict__ scores,
        const float* __restrict__ image, const float* __restrict__ text,
        float* __restrict__ out_text, float* __restrict__ out_img)
{
    const int tid = threadIdx.x, lane = tid & 63, wave = tid >> 6;

    if (blockIdx.x < ATT_P1_BLOCKS) {
        const int bid = blockIdx.x;
        const int csplit = bid & 1;
        const int grp = bid >> 1;            // 0..127
        const int b = grp >> 4;
        const int t0 = (grp & 15) * 8;

        __shared__ float ps[I_TOK][8];
        #pragma unroll
        for (int rr = 0; rr < 2; ++rr) {
            const int tsub = wave + rr * 4;
            const float* srow = scores + ((long)(b * T + t0 + tsub)) * I_TOK;
            const float s0 = srow[lane];
            const float s1 = srow[lane + 64];
            const float s2 = srow[lane + 128];
            const float s3 = (lane < 4) ? srow[lane + 192] : -INFINITY;
            float m = fmaxf(fmaxf(s0, s1), fmaxf(s2, s3));
            #pragma unroll
            for (int off = 32; off; off >>= 1) m = fmaxf(m, __shfl_xor(m, off));
            const float e0 = __expf(s0 - m);
            const float e1 = __expf(s1 - m);
            const float e2 = __expf(s2 - m);
            const float e3 = (lane < 4) ? __expf(s3 - m) : 0.f;
            float sum = e0 + e1 + e2 + e3;
            #pragma unroll
            for (int off = 32; off; off >>= 1) sum += __shfl_xor(sum, off);
            const float inv = __fdividef(1.0f, sum);
            ps[lane][tsub] = e0 * inv;
            ps[lane + 64][tsub] = e1 * inv;
            ps[lane + 128][tsub] = e2 * inv;
            if (lane < 4) ps[lane + 192][tsub] = e3 * inv;
        }
        __syncthreads();

        const float* img = image + (long)b * I_TOK * IMAGE_DIM + csplit * 512 + tid * 2;
        float2 a0 = {0,0}, a1 = {0,0}, a2 = {0,0}, a3 = {0,0};
        float2 a4 = {0,0}, a5 = {0,0}, a6 = {0,0}, a7 = {0,0};

        // 3-set image-row pipeline: A = rows 4g, Bp = rows 4(g+1), tmp = 4(g+2)
        float2 vA0 = *(const float2*)(img + 0 * IMAGE_DIM);
        float2 vA1 = *(const float2*)(img + 1 * IMAGE_DIM);
        float2 vA2 = *(const float2*)(img + 2 * IMAGE_DIM);
        float2 vA3 = *(const float2*)(img + 3 * IMAGE_DIM);
        float2 vB0 = *(const float2*)(img + 4 * IMAGE_DIM);
        float2 vB1 = *(const float2*)(img + 5 * IMAGE_DIM);
        float2 vB2 = *(const float2*)(img + 6 * IMAGE_DIM);
        float2 vB3 = *(const float2*)(img + 7 * IMAGE_DIM);
        float4 pL0 = *(const float4*)&ps[0][0]; float4 pH0 = *(const float4*)&ps[0][4];
        float4 pL1 = *(const float4*)&ps[1][0]; float4 pH1 = *(const float4*)&ps[1][4];
        float4 pL2 = *(const float4*)&ps[2][0]; float4 pH2 = *(const float4*)&ps[2][4];
        float4 pL3 = *(const float4*)&ps[3][0]; float4 pH3 = *(const float4*)&ps[3][4];

        for (int g = 0; g < 49; ++g) {
            const int ib2 = ((g + 2 < 49) ? (g + 2) : 48) * 4;   // 2-ahead (clamped)
            const float2 t0_ = *(const float2*)(img + (long)(ib2 + 0) * IMAGE_DIM);
            const float2 t1_ = *(const float2*)(img + (long)(ib2 + 1) * IMAGE_DIM);
            const float2 t2_ = *(const float2*)(img + (long)(ib2 + 2) * IMAGE_DIM);
            const float2 t3_ = *(const float2*)(img + (long)(ib2 + 3) * IMAGE_DIM);
            const int ibn = ((g + 1 < 49) ? (g + 1) : 48) * 4;   // LDS 1-ahead
            const float4 nL0 = *(const float4*)&ps[ibn + 0][0]; const float4 nH0 = *(const float4*)&ps[ibn + 0][4];
            const float4 nL1 = *(const float4*)&ps[ibn + 1][0]; const float4 nH1 = *(const float4*)&ps[ibn + 1][4];
            const float4 nL2 = *(const float4*)&ps[ibn + 2][0]; const float4 nH2 = *(const float4*)&ps[ibn + 2][4];
            const float4 nL3 = *(const float4*)&ps[ibn + 3][0]; const float4 nH3 = *(const float4*)&ps[ibn + 3][4];

#define ATT_ROW(vr, pl, ph)                                                   \
            a0.x = fmaf(pl.x, vr.x, a0.x); a0.y = fmaf(pl.x, vr.y, a0.y);     \
            a1.x = fmaf(pl.y, vr.x, a1.x); a1.y = fmaf(pl.y, vr.y, a1.y);     \
            a2.x = fmaf(pl.z, vr.x, a2.x); a2.y = fmaf(pl.z, vr.y, a2.y);     \
            a3.x = fmaf(pl.w, vr.x, a3.x); a3.y = fmaf(pl.w, vr.y, a3.y);     \
            a4.x = fmaf(ph.x, vr.x, a4.x); a4.y = fmaf(ph.x, vr.y, a4.y);     \
            a5.x = fmaf(ph.y, vr.x, a5.x); a5.y = fmaf(ph.y, vr.y, a5.y);     \
            a6.x = fmaf(ph.z, vr.x, a6.x); a6.y = fmaf(ph.z, vr.y, a6.y);     \
            a7.x = fmaf(ph.w, vr.x, a7.x); a7.y = fmaf(ph.w, vr.y, a7.y);
            ATT_ROW(vA0, pL0, pH0)
            ATT_ROW(vA1, pL1, pH1)
            ATT_ROW(vA2, pL2, pH2)
            ATT_ROW(vA3, pL3, pH3)
#undef ATT_ROW
            vA0 = vB0; vA1 = vB1; vA2 = vB2; vA3 = vB3;
            vB0 = t0_; vB1 = t1_; vB2 = t2_; vB3 = t3_;
            pL0 = nL0; pH0 = nH0; pL1 = nL1; pH1 = nH1;
            pL2 = nL2; pH2 = nH2; pL3 = nL3; pH3 = nH3;
        }
        float* o = out_text + ((long)(b * T + t0)) * IMAGE_DIM + csplit * 512 + tid * 2;
        *(float2*)(o + 0 * IMAGE_DIM) = a0;
        *(float2*)(o + 1 * IMAGE_DIM) = a1;
        *(float2*)(o + 2 * IMAGE_DIM) = a2;
        *(float2*)(o + 3 * IMAGE_DIM) = a3;
        *(float2*)(o + 4 * IMAGE_DIM) = a4;
        *(float2*)(o + 5 * IMAGE_DIM) = a5;
        *(float2*)(o + 6 * IMAGE_DIM) = a6;
        *(float2*)(o + 7 * IMAGE_DIM) = a7;
    } else {
        const int bid = blockIdx.x - ATT_P1_BLOCKS;
        const int b = bid / 28;
        const int i0 = (bid % 28) * 7;

        __shared__ float qs[T][8];           // col 7 is padding
        for (int cc = wave; cc < 7; cc += 4) {
            const float* sc = scores + (long)b * T * I_TOK + (i0 + cc);
            const float s0 = sc[(long)lane * I_TOK];
            const float s1 = sc[(long)(lane + 64) * I_TOK];
            float m = fmaxf(s0, s1);
            #pragma unroll
            for (int off = 32; off; off >>= 1) m = fmaxf(m, __shfl_xor(m, off));
            const float e0 = __expf(s0 - m);
            const float e1 = __expf(s1 - m);
            float sum = e0 + e1;
            #pragma unroll
            for (int off = 32; off; off >>= 1) sum += __shfl_xor(sum, off);
            const float inv = __fdividef(1.0f, sum);
            qs[lane][cc] = e0 * inv;
            qs[lane + 64][cc] = e1 * inv;
        }
        __syncthreads();

        const float* txt2 = text + (long)b * T * TEXT_DIM + tid * 2;
        const float* txt1 = text + (long)b * T * TEXT_DIM + 512 + tid;
        float ax[7], ay[7], az[7];
        #pragma unroll
        for (int r = 0; r < 7; ++r) { ax[r] = 0.f; ay[r] = 0.f; az[r] = 0.f; }

        // 3-set text-row pipeline: A = rows 2g, Bp = rows 2(g+1), tmp = 2(g+2)
        float2 uA0 = *(const float2*)(txt2 + 0 * TEXT_DIM);
        float2 uA1 = *(const float2*)(txt2 + 1 * TEXT_DIM);
        float  zA0 = txt1[0 * TEXT_DIM];
        float  zA1 = txt1[1 * TEXT_DIM];
        float2 uB0 = *(const float2*)(txt2 + 2 * TEXT_DIM);
        float2 uB1 = *(const float2*)(txt2 + 3 * TEXT_DIM);
        float  zB0 = txt1[2 * TEXT_DIM];
        float  zB1 = txt1[3 * TEXT_DIM];
        float4 qa0 = *(const float4*)&qs[0][0]; float4 qb0 = *(const float4*)&qs[0][4];
        float4 qa1 = *(const float4*)&qs[1][0]; float4 qb1 = *(const float4*)&qs[1][4];

        for (int g = 0; g < 64; ++g) {
            const int tb2 = ((g + 2 < 64) ? (g + 2) : 63) * 2;   // 2-ahead (clamped)
            const float2 tu0 = *(const float2*)(txt2 + (long)(tb2 + 0) * TEXT_DIM);
            const float2 tu1 = *(const float2*)(txt2 + (long)(tb2 + 1) * TEXT_DIM);
            const float  tz0 = txt1[(long)(tb2 + 0) * TEXT_DIM];
            const float  tz1 = txt1[(long)(tb2 + 1) * TEXT_DIM];
            const int tbn = ((g + 1 < 64) ? (g + 1) : 63) * 2;   // LDS 1-ahead
            const float4 na0 = *(const float4*)&qs[tbn + 0][0];
            const float4 nb0 = *(const float4*)&qs[tbn + 0][4];
            const float4 na1 = *(const float4*)&qs[tbn + 1][0];
            const float4 nb1 = *(const float4*)&qs[tbn + 1][4];

            // row 2g
            ax[0] = fmaf(qa0.x, uA0.x, ax[0]); ay[0] = fmaf(qa0.x, uA0.y, ay[0]); az[0] = fmaf(qa0.x, zA0, az[0]);
            ax[1] = fmaf(qa0.y, uA0.x, ax[1]); ay[1] = fmaf(qa0.y, uA0.y, ay[1]); az[1] = fmaf(qa0.y, zA0, az[1]);
            ax[2] = fmaf(qa0.z, uA0.x, ax[2]); ay[2] = fmaf(qa0.z, uA0.y, ay[2]); az[2] = fmaf(qa0.z, zA0, az[2]);
            ax[3] = fmaf(qa0.w, uA0.x, ax[3]); ay[3] = fmaf(qa0.w, uA0.y, ay[3]); az[3] = fmaf(qa0.w, zA0, az[3]);
            ax[4] = fmaf(qb0.x, uA0.x, ax[4]); ay[4] = fmaf(qb0.x, uA0.y, ay[4]); az[4] = fmaf(qb0.x, zA0, az[4]);
            ax[5] = fmaf(qb0.y, uA0.x, ax[5]); ay[5] = fmaf(qb0.y, uA0.y, ay[5]); az[5] = fmaf(qb0.y, zA0, az[5]);
            ax[6] = fmaf(qb0.z, uA0.x, ax[6]); ay[6] = fmaf(qb0.z, uA0.y, ay[6]); az[6] = fmaf(qb0.z, zA0, az[6]);
            // row 2g+1
            ax[0] = fmaf(qa1.x, uA1.x, ax[0]); ay[0] = fmaf(qa1.x, uA1.y, ay[0]); az[0] = fmaf(qa1.x, zA1, az[0]);
            ax[1] = fmaf(qa1.y, uA1.x, ax[1]); ay[1] = fmaf(qa1.y, uA1.y, ay[1]); az[1] = fmaf(qa1.y, zA1, az[1]);
            ax[2] = fmaf(qa1.z, uA1.x, ax[2]); ay[2] = fmaf(qa1.z, uA1.y, ay[2]); az[2] = fmaf(qa1.z, zA1, az[2]);
            ax[3] = fmaf(qa1.w, uA1.x, ax[3]); ay[3] = fmaf(qa1.w, uA1.y, ay[3]); az[3] = fmaf(qa1.w, zA1, az[3]);
            ax[4] = fmaf(qb1.x, uA1.x, ax[4]); ay[4] = fmaf(qb1.x, uA1.y, ay[4]); az[4] = fmaf(qb1.x, zA1, az[4]);
            ax[5] = fmaf(qb1.y, uA1.x, ax[5]); ay[5] = fmaf(qb1.y, uA1.y, ay[5]); az[5] = fmaf(qb1.y, zA1, az[5]);
            ax[6] = fmaf(qb1.z, uA1.x, ax[6]); ay[6] = fmaf(qb1.z, uA1.y, ay[6]); az[6] = fmaf(qb1.z, zA1, az[6]);

            uA0 = uB0; uA1 = uB1; zA0 = zB0; zA1 = zB1;
            uB0 = tu0; uB1 = tu1; zB0 = tz0; zB1 = tz1;
            qa0 = na0; qb0 = nb0; qa1 = na1; qb1 = nb1;
        }
        float* o = out_img + ((long)b * I_TOK + i0) * TEXT_DIM;
        #pragma unroll
        for (int r = 0; r < 7; ++r) {
            float2 w;
            w.x = ax[r]; w.y = ay[r];
            *(float2*)(o + (long)r * TEXT_DIM + tid * 2) = w;
            o[(long)r * TEXT_DIM + 512 + tid] = az[r];
        }
    }
}

extern "C" void kernel_launch(void* const* d_in, const int* in_sizes, int n_in,
                              void* d_out, int out_size, void* d_ws, size_t ws_size,
                              hipStream_t stream) {
    const float* text  = (const float*)d_in[0];
    const float* image = (const float*)d_in[1];
    const float* Wt    = (const float*)d_in[2];
    const float* bt    = (const float*)d_in[3];
    const float* Wi    = (const float*)d_in[4];
    const float* bi    = (const float*)d_in[5];
    const float* wa    = (const float*)d_in[6];
    const float* ba    = (const float*)d_in[7];

    float* pt = (float*)d_ws;                       // Et = exp2-transformed
    float* pi = pt + (long)B * T * HIDDEN;          // Ei
    float* sc = pi + (long)B * I_TOK * HIDDEN;
    unsigned short* Xh  = (unsigned short*)(sc + (long)B * T * I_TOK);
    unsigned short* Xl  = Xh + X_ELEMS;
    unsigned short* WTh = Xl + X_ELEMS;
    unsigned short* WTl = WTh + W_ELEMS;

    float* out_text = (float*)d_out;                        // B*T*IMAGE_DIM
    float* out_img  = out_text + (long)B * T * IMAGE_DIM;   // B*I*TEXT_DIM

    prep_kernel<<<PREP_GRID, 256, 0, stream>>>(text, image, Wt, Wi, Xh, Xl, WTh, WTl);
    mfma_proj_kernel<<<GEMM_GRID, 256, 0, stream>>>(Xh, Xl, WTh, WTl, bt, bi, pt, pi);
    scores_kernel<<<2 * B * T, 256, 0, stream>>>(pt, pi, wa, ba, sc);
    att_kernel<<<ATT_GRID, 256, 0, stream>>>(sc, image, text, out_text, out_img);
}

// Round 7
// 131.510 us; speedup vs baseline: 2.7470x; 1.0428x over previous
//
#include <hip/hip_runtime.h>
#include <math.h>

#define B 8
#define T 128
#define I_TOK 196
#define TEXT_DIM 768
#define IMAGE_DIM 1024
#define HIDDEN 512
#define EXP_SCALE 2.88539008177792681f   // 2*log2(e): exp(2x) = 2^(EXP_SCALE*x)

#if __has_builtin(__builtin_amdgcn_exp2f)
#define FAST_EXP2(x) __builtin_amdgcn_exp2f(x)
#else
#define FAST_EXP2(x) exp2f(x)
#endif
#if __has_builtin(__builtin_amdgcn_rcpf)
#define FAST_RCP(x) __builtin_amdgcn_rcpf(x)
#else
#define FAST_RCP(x) __fdividef(1.f, (x))
#endif

typedef short bf16x8 __attribute__((ext_vector_type(8)));
typedef float f32x4 __attribute__((ext_vector_type(4)));

typedef __attribute__((address_space(3))) void       as3_void;
typedef __attribute__((address_space(1))) const void as1_cvoid;

// ---- fragment-tiled layout geometry ---------------------------------------
#define KT_T (TEXT_DIM / 32)     // 24 k-tiles (text)
#define KT_I (IMAGE_DIM / 32)    // 32 k-tiles (image)
#define MT_T (B * T / 16)        // 64 m-tiles (text rows)
#define MT_I (B * I_TOK / 16)    // 98 m-tiles (image rows)
#define NT   (HIDDEN / 16)       // 32 n-tiles (W columns)

#define XT_ELEMS (MT_T * KT_T * 512)       // 786432
#define XI_ELEMS (MT_I * KT_I * 512)       // 1605632
#define X_ELEMS  (XT_ELEMS + XI_ELEMS)
#define WT_T_ELEMS (NT * KT_T * 512)       // 393216
#define W_ELEMS (WT_T_ELEMS + NT * KT_I * 512)

#define XTILES_T (MT_T * KT_T)             // 1536
#define XTILES   (XTILES_T + MT_I * KT_I)  // 4672
#define WTILES_T (NT * KT_T)               // 768
#define WTILES   (WTILES_T + NT * KT_I)    // 1792
#define PREP_GRID ((XTILES + WTILES) / 4)  // 1616 blocks, 1 tile per wave

__device__ __forceinline__ unsigned short f2bf(float x) {
    unsigned int u = __float_as_uint(x);
    unsigned int r = u + 0x7FFFu + ((u >> 16) & 1u);   // RNE
    return (unsigned short)(r >> 16);
}
__device__ __forceinline__ float bf2f(unsigned short h) {
    return __uint_as_float(((unsigned int)h) << 16);
}

// ---------------- prep v9: split-bf16 + fragment-tiling (unchanged) --------
__global__ __launch_bounds__(256) void prep_kernel(
        const float* __restrict__ text, const float* __restrict__ image,
        const float* __restrict__ Wt, const float* __restrict__ Wi,
        unsigned short* __restrict__ Xh, unsigned short* __restrict__ Xl,
        unsigned short* __restrict__ WTh, unsigned short* __restrict__ WTl)
{
    const int tid = threadIdx.x;
    const int lane = tid & 63, wv = tid >> 6;
    const int r16 = lane & 15, quad = lane >> 4;
    const int id = blockIdx.x * 4 + wv;

    float v[8];
    unsigned short* oh;
    unsigned short* ol;
    long dst;

    if (id < XTILES) {
        const float* X; int K, mt, kt;
        if (id < XTILES_T) { X = text; K = TEXT_DIM; mt = id / KT_T; kt = id % KT_T; }
        else { const int i2 = id - XTILES_T; X = image; K = IMAGE_DIM; mt = i2 / KT_I; kt = i2 % KT_I; }
        const float* src = X + (long)(mt * 16 + r16) * K + kt * 32 + quad * 8;
        const float4 a = *(const float4*)src;
        const float4 b = *(const float4*)(src + 4);
        v[0]=a.x; v[1]=a.y; v[2]=a.z; v[3]=a.w; v[4]=b.x; v[5]=b.y; v[6]=b.z; v[7]=b.w;
        oh = (id < XTILES_T) ? Xh : Xh + XT_ELEMS;
        ol = (id < XTILES_T) ? Xl : Xl + XT_ELEMS;
        const long tile = (id < XTILES_T) ? id : (long)(id - XTILES_T);
        dst = tile * 512 + lane * 8;
    } else {
        const int idw = id - XTILES;
        const float* W; int K, nt, kt;
        if (idw < WTILES_T) { W = Wt; K = TEXT_DIM; nt = idw / KT_T; kt = idw % KT_T; }
        else { const int i2 = idw - WTILES_T; W = Wi; K = IMAGE_DIM; nt = i2 / KT_I; kt = i2 % KT_I; }
        const float* src = W + (long)(kt * 32 + quad * 8) * HIDDEN + nt * 16 + r16;
        #pragma unroll
        for (int j = 0; j < 8; ++j) v[j] = src[(long)j * HIDDEN];
        oh = (idw < WTILES_T) ? WTh : WTh + WT_T_ELEMS;
        ol = (idw < WTILES_T) ? WTl : WTl + WT_T_ELEMS;
        const long tile = (idw < WTILES_T) ? idw : (long)(idw - WTILES_T);
        dst = tile * 512 + lane * 8;
    }

    uint4 hv, lv;
    unsigned int hh[8], ll[8];
    #pragma unroll
    for (int j = 0; j < 8; ++j) {
        hh[j] = f2bf(v[j]);
        ll[j] = f2bf(v[j] - bf2f((unsigned short)hh[j]));
    }
    hv.x = hh[0] | (hh[1] << 16); hv.y = hh[2] | (hh[3] << 16);
    hv.z = hh[4] | (hh[5] << 16); hv.w = hh[6] | (hh[7] << 16);
    lv.x = ll[0] | (ll[1] << 16); lv.y = ll[2] | (ll[3] << 16);
    lv.z = ll[4] | (ll[5] << 16); lv.w = ll[6] | (ll[7] << 16);
    *(uint4*)(oh + dst) = hv;
    *(uint4*)(ol + dst) = lv;
}

// ---------------- MFMA projections v12: 4-buffer counted-vmcnt pipeline ----
// Depth 3 covered ~200cy of the ~300+cy L3-hit latency (fill evicts L3 each
// iteration). Depth 4 (64KB LDS, still 2 blocks/CU) + vmcnt 12/8/4/0 ladder
// covers it fully. MFMA order per accumulator unchanged -> bit-identical.
#define GT2_BLOCKS (16 * 8)                  // 128 (text: 16 m-groups x 8 n)
#define GI2_BLOCKS (25 * 8)                  // 200 (image: 25 m-groups x 8 n)
#define GEMM_GRID (GT2_BLOCKS + GI2_BLOCKS)  // 328

__global__ __launch_bounds__(256, 2) void mfma_proj_kernel(
        const unsigned short* __restrict__ Xh, const unsigned short* __restrict__ Xl,
        const unsigned short* __restrict__ WTh, const unsigned short* __restrict__ WTl,
        const float* __restrict__ bt, const float* __restrict__ bi,
        float* __restrict__ pt, float* __restrict__ pi)
{
    // slots 0-3: Ah(mt0..mt0+3)  4-7: Al  8-11: Bh(nt0..nt0+3)  12-15: Bl
    __shared__ __align__(16) unsigned short lds[4][16][512];   // 64 KB

    const int tid = threadIdx.x;
    const int lane = tid & 63, wv = tid >> 6;
    const int r16 = lane & 15, quad = lane >> 4;
    const int wr = wv >> 1, wc = wv & 1;     // wave tile in 2x2 grid

    // XCD-aware bijective swizzle
    const int bid0 = blockIdx.x;
    int bid;
    if (bid0 < GT2_BLOCKS) bid = (bid0 & 7) * 16 + (bid0 >> 3);
    else { const int d = bid0 - GT2_BLOCKS; bid = GT2_BLOCKS + (d & 7) * 25 + (d >> 3); }

    const unsigned short *xh, *xl, *wh, *wl; const float* bias; float* Y;
    int ktiles, mt0, n8;
    if (bid < GT2_BLOCKS) {
        xh = Xh; xl = Xl; wh = WTh; wl = WTl; bias = bt; Y = pt; ktiles = KT_T;
        mt0 = (bid >> 3) * 4; n8 = bid & 7;
    } else {
        const int ib = bid - GT2_BLOCKS;
        xh = Xh + XT_ELEMS; xl = Xl + XT_ELEMS;
        wh = WTh + WT_T_ELEMS; wl = WTl + WT_T_ELEMS;
        bias = bi; Y = pi; ktiles = KT_I;
        const int mg = ib >> 3;
        mt0 = (mg == 24) ? (MT_I - 4) : mg * 4;   // tail overlaps (bit-identical)
        n8 = ib & 7;
    }
    const int nt0 = n8 * 4;

    const unsigned short* ssrc[4];
    #pragma unroll
    for (int q = 0; q < 4; ++q) {
        const int t = wv * 4 + q;
        const int g = t >> 2;            // 0:Ah 1:Al 2:Bh 3:Bl
        const int i = t & 3;
        const unsigned short* base = (g == 0) ? xh : (g == 1) ? xl : (g == 2) ? wh : wl;
        const long row = (g < 2) ? (long)(mt0 + i) : (long)(nt0 + i);
        ssrc[q] = base + row * ktiles * 512 + lane * 8;
    }

#define STAGE(buf, kt) do {                                                    \
        _Pragma("unroll")                                                      \
        for (int q_ = 0; q_ < 4; ++q_) {                                       \
            __builtin_amdgcn_global_load_lds(                                  \
                (as1_cvoid*)(ssrc[q_] + (long)(kt) * 512),                     \
                (as3_void*)&lds[buf][wv * 4 + q_][0], 16, 0, 0);               \
        } } while (0)

    f32x4 a00 = {0,0,0,0}, a01 = {0,0,0,0}, a10 = {0,0,0,0}, a11 = {0,0,0,0};

    // prologue: 4 stages in flight (ktiles is 24 or 32, always >= 4)
    STAGE(0, 0);
    STAGE(1, 1);
    STAGE(2, 2);
    STAGE(3, 3);

    for (int s = 0; s < ktiles; ++s) {
        // stage s must be complete; up to 3 later stages (4 loads each) fly
        if (s + 3 < ktiles)      asm volatile("s_waitcnt vmcnt(12)" ::: "memory");
        else if (s + 2 < ktiles) asm volatile("s_waitcnt vmcnt(8)" ::: "memory");
        else if (s + 1 < ktiles) asm volatile("s_waitcnt vmcnt(4)" ::: "memory");
        else                     asm volatile("s_waitcnt vmcnt(0)" ::: "memory");
        __builtin_amdgcn_s_barrier();      // all waves' stage-s data visible

        const int cur = s & 3;
        const int fo = lane * 8;
        const bf16x8 Ah0 = *(const bf16x8*)&lds[cur][wr * 2 + 0][fo];
        const bf16x8 Ah1 = *(const bf16x8*)&lds[cur][wr * 2 + 1][fo];
        const bf16x8 Al0 = *(const bf16x8*)&lds[cur][4 + wr * 2 + 0][fo];
        const bf16x8 Al1 = *(const bf16x8*)&lds[cur][4 + wr * 2 + 1][fo];
        const bf16x8 Bh0 = *(const bf16x8*)&lds[cur][8 + wc * 2 + 0][fo];
        const bf16x8 Bh1 = *(const bf16x8*)&lds[cur][8 + wc * 2 + 1][fo];
        const bf16x8 Bl0 = *(const bf16x8*)&lds[cur][12 + wc * 2 + 0][fo];
        const bf16x8 Bl1 = *(const bf16x8*)&lds[cur][12 + wc * 2 + 1][fo];

        a00 = __builtin_amdgcn_mfma_f32_16x16x32_bf16(Ah0, Bh0, a00, 0, 0, 0);
        a01 = __builtin_amdgcn_mfma_f32_16x16x32_bf16(Ah0, Bh1, a01, 0, 0, 0);
        a10 = __builtin_amdgcn_mfma_f32_16x16x32_bf16(Ah1, Bh0, a10, 0, 0, 0);
        a11 = __builtin_amdgcn_mfma_f32_16x16x32_bf16(Ah1, Bh1, a11, 0, 0, 0);
        a00 = __builtin_amdgcn_mfma_f32_16x16x32_bf16(Ah0, Bl0, a00, 0, 0, 0);
        a01 = __builtin_amdgcn_mfma_f32_16x16x32_bf16(Ah0, Bl1, a01, 0, 0, 0);
        a10 = __builtin_amdgcn_mfma_f32_16x16x32_bf16(Ah1, Bl0, a10, 0, 0, 0);
        a11 = __builtin_amdgcn_mfma_f32_16x16x32_bf16(Ah1, Bl1, a11, 0, 0, 0);
        a00 = __builtin_amdgcn_mfma_f32_16x16x32_bf16(Al0, Bh0, a00, 0, 0, 0);
        a01 = __builtin_amdgcn_mfma_f32_16x16x32_bf16(Al0, Bh1, a01, 0, 0, 0);
        a10 = __builtin_amdgcn_mfma_f32_16x16x32_bf16(Al1, Bh0, a10, 0, 0, 0);
        a11 = __builtin_amdgcn_mfma_f32_16x16x32_bf16(Al1, Bh1, a11, 0, 0, 0);

        __builtin_amdgcn_s_barrier();      // all waves done reading buf cur
        if (s + 4 < ktiles) STAGE(cur, s + 4);
    }
#undef STAGE

    const int row00 = (mt0 + wr * 2) * 16 + quad * 4;
    const int col0  = (nt0 + wc * 2) * 16 + r16;
    const float bv0 = bias[col0];
    const float bv1 = bias[col0 + 16];
    #pragma unroll
    for (int r = 0; r < 4; ++r) {
        Y[(long)(row00 + r)      * HIDDEN + col0]      = FAST_EXP2((a00[r] + bv0) * EXP_SCALE);
        Y[(long)(row00 + r)      * HIDDEN + col0 + 16] = FAST_EXP2((a01[r] + bv1) * EXP_SCALE);
        Y[(long)(row00 + 16 + r) * HIDDEN + col0]      = FAST_EXP2((a10[r] + bv0) * EXP_SCALE);
        Y[(long)(row00 + 16 + r) * HIDDEN + col0 + 16] = FAST_EXP2((a11[r] + bv1) * EXP_SCALE);
    }
}

// ---------------- Scores v10 (unchanged from R6) ---------------------------
__global__ __launch_bounds__(256, 6) void scores_kernel(const float* __restrict__ pt,
        const float* __restrict__ pi, const float* __restrict__ wa,
        const float* __restrict__ ba, float* __restrict__ scores)
{
    const int blk = blockIdx.x;              // 0..2047
    const int chunk = blk & 3;
    const int bt0 = (blk >> 2) * 2;          // even text-row index
    const int b = bt0 >> 7;                  // /T
    const int tid = threadIdx.x;
    const int lane = tid & 63, wave = tid >> 6;

    const float* ptrow = pt + (long)bt0 * HIDDEN + lane * 8;
    const float4 pA0 = *(const float4*)ptrow;
    const float4 pB0 = *(const float4*)(ptrow + 4);
    const float4 pA1 = *(const float4*)(ptrow + HIDDEN);
    const float4 pB1 = *(const float4*)(ptrow + HIDDEN + 4);
    float4 wA = *(const float4*)(wa + lane * 8);
    float4 wB = *(const float4*)(wa + lane * 8 + 4);

    float S = wA.x + wA.y + wA.z + wA.w + wB.x + wB.y + wB.z + wB.w;
    #pragma unroll
    for (int off = 32; off; off >>= 1) S += __shfl_down(S, off);
    const float base = S + ba[0];

    wA.x *= -2.f; wA.y *= -2.f; wA.z *= -2.f; wA.w *= -2.f;
    wB.x *= -2.f; wB.y *= -2.f; wB.z *= -2.f; wB.w *= -2.f;

    const float* pib = pi + (long)b * I_TOK * HIDDEN + lane * 8;
    const int i0 = chunk * 49 + wave;
    const int iend = chunk * 49 + 49;

    float4 ca = *(const float4*)(pib + (long)i0 * HIDDEN);
    float4 cb = *(const float4*)(pib + (long)i0 * HIDDEN + 4);

    for (int i = i0; i < iend; i += 4) {
        const int inx = (i + 4 < iend) ? (i + 4) : i;
        const float4 na = *(const float4*)(pib + (long)inx * HIDDEN);
        const float4 nb = *(const float4*)(pib + (long)inx * HIDDEN + 4);

        float acc0 = 0.f;
        acc0 = fmaf(wA.x, FAST_RCP(fmaf(pA0.x, ca.x, 1.f)), acc0);
        acc0 = fmaf(wA.y, FAST_RCP(fmaf(pA0.y, ca.y, 1.f)), acc0);
        acc0 = fmaf(wA.z, FAST_RCP(fmaf(pA0.z, ca.z, 1.f)), acc0);
        acc0 = fmaf(wA.w, FAST_RCP(fmaf(pA0.w, ca.w, 1.f)), acc0);
        acc0 = fmaf(wB.x, FAST_RCP(fmaf(pB0.x, cb.x, 1.f)), acc0);
        acc0 = fmaf(wB.y, FAST_RCP(fmaf(pB0.y, cb.y, 1.f)), acc0);
        acc0 = fmaf(wB.z, FAST_RCP(fmaf(pB0.z, cb.z, 1.f)), acc0);
        acc0 = fmaf(wB.w, FAST_RCP(fmaf(pB0.w, cb.w, 1.f)), acc0);

        float acc1 = 0.f;
        acc1 = fmaf(wA.x, FAST_RCP(fmaf(pA1.x, ca.x, 1.f)), acc1);
        acc1 = fmaf(wA.y, FAST_RCP(fmaf(pA1.y, ca.y, 1.f)), acc1);
        acc1 = fmaf(wA.z, FAST_RCP(fmaf(pA1.z, ca.z, 1.f)), acc1);
        acc1 = fmaf(wA.w, FAST_RCP(fmaf(pA1.w, ca.w, 1.f)), acc1);
        acc1 = fmaf(wB.x, FAST_RCP(fmaf(pB1.x, cb.x, 1.f)), acc1);
        acc1 = fmaf(wB.y, FAST_RCP(fmaf(pB1.y, cb.y, 1.f)), acc1);
        acc1 = fmaf(wB.z, FAST_RCP(fmaf(pB1.z, cb.z, 1.f)), acc1);
        acc1 = fmaf(wB.w, FAST_RCP(fmaf(pB1.w, cb.w, 1.f)), acc1);

        #pragma unroll
        for (int off = 32; off; off >>= 1) {
            acc0 += __shfl_down(acc0, off);
            acc1 += __shfl_down(acc1, off);
        }
        if (lane == 0) {
            scores[(long)bt0 * I_TOK + i]       = base + acc0;
            scores[(long)(bt0 + 1) * I_TOK + i] = base + acc1;
        }
        ca = na; cb = nb;
    }
}

// ---------------- Fused attended outputs v11: P1 csplit4 (TLP x2) ----------
// P1 was 1 block/CU (1 wave/SIMD) -> every L3-hit load stalled the SIMD.
// csplit 2->4: 512 P1 blocks, 1 col/thread; with P2's 224 -> 736 blocks
// (~2.9/CU, ~3 waves/SIMD). Per-output accumulation order unchanged.
#define ATT_P1_BLOCKS 512                    // 8b * 16 grp * 4 csplit
#define ATT_P2_BLOCKS (B * 28)               // 196 = 28 * 7
#define ATT_GRID (ATT_P1_BLOCKS + ATT_P2_BLOCKS)   // 736

__global__ __launch_bounds__(256) void att_kernel(const float* __restrict__ scores,
        const float* __restrict__ image, const float* __restrict__ text,
        float* __restrict__ out_text, float* __restrict__ out_img)
{
    const int tid = threadIdx.x, lane = tid & 63, wave = tid >> 6;

    if (blockIdx.x < ATT_P1_BLOCKS) {
        const int bid = blockIdx.x;
        const int csplit = bid & 3;
        const int grp = bid >> 2;            // 0..127
        const int b = grp >> 4;
        const int t0 = (grp & 15) * 8;

        __shared__ float ps[I_TOK][8];
        #pragma unroll
        for (int rr = 0; rr < 2; ++rr) {
            const int tsub = wave + rr * 4;
            const float* srow = scores + ((long)(b * T + t0 + tsub)) * I_TOK;
            const float s0 = srow[lane];
            const float s1 = srow[lane + 64];
            const float s2 = srow[lane + 128];
            const float s3 = (lane < 4) ? srow[lane + 192] : -INFINITY;
            float m = fmaxf(fmaxf(s0, s1), fmaxf(s2, s3));
            #pragma unroll
            for (int off = 32; off; off >>= 1) m = fmaxf(m, __shfl_xor(m, off));
            const float e0 = __expf(s0 - m);
            const float e1 = __expf(s1 - m);
            const float e2 = __expf(s2 - m);
            const float e3 = (lane < 4) ? __expf(s3 - m) : 0.f;
            float sum = e0 + e1 + e2 + e3;
            #pragma unroll
            for (int off = 32; off; off >>= 1) sum += __shfl_xor(sum, off);
            const float inv = __fdividef(1.0f, sum);
            ps[lane][tsub] = e0 * inv;
            ps[lane + 64][tsub] = e1 * inv;
            ps[lane + 128][tsub] = e2 * inv;
            if (lane < 4) ps[lane + 192][tsub] = e3 * inv;
        }
        __syncthreads();

        const float* img = image + (long)b * I_TOK * IMAGE_DIM + csplit * 256 + tid;
        float a0 = 0.f, a1 = 0.f, a2 = 0.f, a3 = 0.f;
        float a4 = 0.f, a5 = 0.f, a6 = 0.f, a7 = 0.f;

        // 3-set image-row pipeline (2-deep prefetch), 1 col/thread
        float vA0 = img[0 * IMAGE_DIM];
        float vA1 = img[1 * IMAGE_DIM];
        float vA2 = img[2 * IMAGE_DIM];
        float vA3 = img[3 * IMAGE_DIM];
        float vB0 = img[4 * IMAGE_DIM];
        float vB1 = img[5 * IMAGE_DIM];
        float vB2 = img[6 * IMAGE_DIM];
        float vB3 = img[7 * IMAGE_DIM];
        float4 pL0 = *(const float4*)&ps[0][0]; float4 pH0 = *(const float4*)&ps[0][4];
        float4 pL1 = *(const float4*)&ps[1][0]; float4 pH1 = *(const float4*)&ps[1][4];
        float4 pL2 = *(const float4*)&ps[2][0]; float4 pH2 = *(const float4*)&ps[2][4];
        float4 pL3 = *(const float4*)&ps[3][0]; float4 pH3 = *(const float4*)&ps[3][4];

        for (int g = 0; g < 49; ++g) {
            const int ib2 = ((g + 2 < 49) ? (g + 2) : 48) * 4;   // 2-ahead (clamped)
            const float t0_ = img[(long)(ib2 + 0) * IMAGE_DIM];
            const float t1_ = img[(long)(ib2 + 1) * IMAGE_DIM];
            const float t2_ = img[(long)(ib2 + 2) * IMAGE_DIM];
            const float t3_ = img[(long)(ib2 + 3) * IMAGE_DIM];
            const int ibn = ((g + 1 < 49) ? (g + 1) : 48) * 4;   // LDS 1-ahead
            const float4 nL0 = *(const float4*)&ps[ibn + 0][0]; const float4 nH0 = *(const float4*)&ps[ibn + 0][4];
            const float4 nL1 = *(const float4*)&ps[ibn + 1][0]; const float4 nH1 = *(const float4*)&ps[ibn + 1][4];
            const float4 nL2 = *(const float4*)&ps[ibn + 2][0]; const float4 nH2 = *(const float4*)&ps[ibn + 2][4];
            const float4 nL3 = *(const float4*)&ps[ibn + 3][0]; const float4 nH3 = *(const float4*)&ps[ibn + 3][4];

#define ATT_ROW(vr, pl, ph)                                                   \
            a0 = fmaf(pl.x, vr, a0); a1 = fmaf(pl.y, vr, a1);                 \
            a2 = fmaf(pl.z, vr, a2); a3 = fmaf(pl.w, vr, a3);                 \
            a4 = fmaf(ph.x, vr, a4); a5 = fmaf(ph.y, vr, a5);                 \
            a6 = fmaf(ph.z, vr, a6); a7 = fmaf(ph.w, vr, a7);
            ATT_ROW(vA0, pL0, pH0)
            ATT_ROW(vA1, pL1, pH1)
            ATT_ROW(vA2, pL2, pH2)
            ATT_ROW(vA3, pL3, pH3)
#undef ATT_ROW
            vA0 = vB0; vA1 = vB1; vA2 = vB2; vA3 = vB3;
            vB0 = t0_; vB1 = t1_; vB2 = t2_; vB3 = t3_;
            pL0 = nL0; pH0 = nH0; pL1 = nL1; pH1 = nH1;
            pL2 = nL2; pH2 = nH2; pL3 = nL3; pH3 = nH3;
        }
        float* o = out_text + ((long)(b * T + t0)) * IMAGE_DIM + csplit * 256 + tid;
        o[0 * IMAGE_DIM] = a0;
        o[1 * IMAGE_DIM] = a1;
        o[2 * IMAGE_DIM] = a2;
        o[3 * IMAGE_DIM] = a3;
        o[4 * IMAGE_DIM] = a4;
        o[5 * IMAGE_DIM] = a5;
        o[6 * IMAGE_DIM] = a6;
        o[7 * IMAGE_DIM] = a7;
    } else {
        const int bid = blockIdx.x - ATT_P1_BLOCKS;
        const int b = bid / 28;
        const int i0 = (bid % 28) * 7;

        __shared__ float qs[T][8];           // col 7 is padding
        for (int cc = wave; cc < 7; cc += 4) {
            const float* sc = scores + (long)b * T * I_TOK + (i0 + cc);
            const float s0 = sc[(long)lane * I_TOK];
            const float s1 = sc[(long)(lane + 64) * I_TOK];
            float m = fmaxf(s0, s1);
            #pragma unroll
            for (int off = 32; off; off >>= 1) m = fmaxf(m, __shfl_xor(m, off));
            const float e0 = __expf(s0 - m);
            const float e1 = __expf(s1 - m);
            float sum = e0 + e1;
            #pragma unroll
            for (int off = 32; off; off >>= 1) sum += __shfl_xor(sum, off);
            const float inv = __fdividef(1.0f, sum);
            qs[lane][cc] = e0 * inv;
            qs[lane + 64][cc] = e1 * inv;
        }
        __syncthreads();

        const float* txt2 = text + (long)b * T * TEXT_DIM + tid * 2;
        const float* txt1 = text + (long)b * T * TEXT_DIM + 512 + tid;
        float ax[7], ay[7], az[7];
        #pragma unroll
        for (int r = 0; r < 7; ++r) { ax[r] = 0.f; ay[r] = 0.f; az[r] = 0.f; }

        // 3-set text-row pipeline (2-deep prefetch)
        float2 uA0 = *(const float2*)(txt2 + 0 * TEXT_DIM);
        float2 uA1 = *(const float2*)(txt2 + 1 * TEXT_DIM);
        float  zA0 = txt1[0 * TEXT_DIM];
        float  zA1 = txt1[1 * TEXT_DIM];
        float2 uB0 = *(const float2*)(txt2 + 2 * TEXT_DIM);
        float2 uB1 = *(const float2*)(txt2 + 3 * TEXT_DIM);
        float  zB0 = txt1[2 * TEXT_DIM];
        float  zB1 = txt1[3 * TEXT_DIM];
        float4 qa0 = *(const float4*)&qs[0][0]; float4 qb0 = *(const float4*)&qs[0][4];
        float4 qa1 = *(const float4*)&qs[1][0]; float4 qb1 = *(const float4*)&qs[1][4];

        for (int g = 0; g < 64; ++g) {
            const int tb2 = ((g + 2 < 64) ? (g + 2) : 63) * 2;   // 2-ahead (clamped)
            const float2 tu0 = *(const float2*)(txt2 + (long)(tb2 + 0) * TEXT_DIM);
            const float2 tu1 = *(const float2*)(txt2 + (long)(tb2 + 1) * TEXT_DIM);
            const float  tz0 = txt1[(long)(tb2 + 0) * TEXT_DIM];
            const float  tz1 = txt1[(long)(tb2 + 1) * TEXT_DIM];
            const int tbn = ((g + 1 < 64) ? (g + 1) : 63) * 2;   // LDS 1-ahead
            const float4 na0 = *(const float4*)&qs[tbn + 0][0];
            const float4 nb0 = *(const float4*)&qs[tbn + 0][4];
            const float4 na1 = *(const float4*)&qs[tbn + 1][0];
            const float4 nb1 = *(const float4*)&qs[tbn + 1][4];

            // row 2g
            ax[0] = fmaf(qa0.x, uA0.x, ax[0]); ay[0] = fmaf(qa0.x, uA0.y, ay[0]); az[0] = fmaf(qa0.x, zA0, az[0]);
            ax[1] = fmaf(qa0.y, uA0.x, ax[1]); ay[1] = fmaf(qa0.y, uA0.y, ay[1]); az[1] = fmaf(qa0.y, zA0, az[1]);
            ax[2] = fmaf(qa0.z, uA0.x, ax[2]); ay[2] = fmaf(qa0.z, uA0.y, ay[2]); az[2] = fmaf(qa0.z, zA0, az[2]);
            ax[3] = fmaf(qa0.w, uA0.x, ax[3]); ay[3] = fmaf(qa0.w, uA0.y, ay[3]); az[3] = fmaf(qa0.w, zA0, az[3]);
            ax[4] = fmaf(qb0.x, uA0.x, ax[4]); ay[4] = fmaf(qb0.x, uA0.y, ay[4]); az[4] = fmaf(qb0.x, zA0, az[4]);
            ax[5] = fmaf(qb0.y, uA0.x, ax[5]); ay[5] = fmaf(qb0.y, uA0.y, ay[5]); az[5] = fmaf(qb0.y, zA0, az[5]);
            ax[6] = fmaf(qb0.z, uA0.x, ax[6]); ay[6] = fmaf(qb0.z, uA0.y, ay[6]); az[6] = fmaf(qb0.z, zA0, az[6]);
            // row 2g+1
            ax[0] = fmaf(qa1.x, uA1.x, ax[0]); ay[0] = fmaf(qa1.x, uA1.y, ay[0]); az[0] = fmaf(qa1.x, zA1, az[0]);
            ax[1] = fmaf(qa1.y, uA1.x, ax[1]); ay[1] = fmaf(qa1.y, uA1.y, ay[1]); az[1] = fmaf(qa1.y, zA1, az[1]);
            ax[2] = fmaf(qa1.z, uA1.x, ax[2]); ay[2] = fmaf(qa1.z, uA1.y, ay[2]); az[2] = fmaf(qa1.z, zA1, az[2]);
            ax[3] = fmaf(qa1.w, uA1.x, ax[3]); ay[3] = fmaf(qa1.w, uA1.y, ay[3]); az[3] = fmaf(qa1.w, zA1, az[3]);
            ax[4] = fmaf(qb1.x, uA1.x, ax[4]); ay[4] = fmaf(qb1.x, uA1.y, ay[4]); az[4] = fmaf(qb1.x, zA1, az[4]);
            ax[5] = fmaf(qb1.y, uA1.x, ax[5]); ay[5] = fmaf(qb1.y, uA1.y, ay[5]); az[5] = fmaf(qb1.y, zA1, az[5]);
            ax[6] = fmaf(qb1.z, uA1.x, ax[6]); ay[6] = fmaf(qb1.z, uA1.y, ay[6]); az[6] = fmaf(qb1.z, zA1, az[6]);

            uA0 = uB0; uA1 = uB1; zA0 = zB0; zA1 = zB1;
            uB0 = tu0; uB1 = tu1; zB0 = tz0; zB1 = tz1;
            qa0 = na0; qb0 = nb0; qa1 = na1; qb1 = nb1;
        }
        float* o = out_img + ((long)b * I_TOK + i0) * TEXT_DIM;
        #pragma unroll
        for (int r = 0; r < 7; ++r) {
            float2 w;
            w.x = ax[r]; w.y = ay[r];
            *(float2*)(o + (long)r * TEXT_DIM + tid * 2) = w;
            o[(long)r * TEXT_DIM + 512 + tid] = az[r];
        }
    }
}

extern "C" void kernel_launch(void* const* d_in, const int* in_sizes, int n_in,
                              void* d_out, int out_size, void* d_ws, size_t ws_size,
                              hipStream_t stream) {
    const float* text  = (const float*)d_in[0];
    const float* image = (const float*)d_in[1];
    const float* Wt    = (const float*)d_in[2];
    const float* bt    = (const float*)d_in[3];
    const float* Wi    = (const float*)d_in[4];
    const float* bi    = (const float*)d_in[5];
    const float* wa    = (const float*)d_in[6];
    const float* ba    = (const float*)d_in[7];

    float* pt = (float*)d_ws;                       // Et = exp2-transformed
    float* pi = pt + (long)B * T * HIDDEN;          // Ei
    float* sc = pi + (long)B * I_TOK * HIDDEN;
    unsigned short* Xh  = (unsigned short*)(sc + (long)B * T * I_TOK);
    unsigned short* Xl  = Xh + X_ELEMS;
    unsigned short* WTh = Xl + X_ELEMS;
    unsigned short* WTl = WTh + W_ELEMS;

    float* out_text = (float*)d_out;                        // B*T*IMAGE_DIM
    float* out_img  = out_text + (long)B * T * IMAGE_DIM;   // B*I*TEXT_DIM

    prep_kernel<<<PREP_GRID, 256, 0, stream>>>(text, image, Wt, Wi, Xh, Xl, WTh, WTl);
    mfma_proj_kernel<<<GEMM_GRID, 256, 0, stream>>>(Xh, Xl, WTh, WTl, bt, bi, pt, pi);
    scores_kernel<<<2 * B * T, 256, 0, stream>>>(pt, pi, wa, ba, sc);
    att_kernel<<<ATT_GRID, 256, 0, stream>>>(sc, image, text, out_text, out_img);
}

// Round 8
// 130.575 us; speedup vs baseline: 2.7667x; 1.0072x over previous
//
#include <hip/hip_runtime.h>
#include <math.h>

#define B 8
#define T 128
#define I_TOK 196
#define TEXT_DIM 768
#define IMAGE_DIM 1024
#define HIDDEN 512
#define EXP_SCALE 2.88539008177792681f   // 2*log2(e): exp(2x) = 2^(EXP_SCALE*x)

#if __has_builtin(__builtin_amdgcn_exp2f)
#define FAST_EXP2(x) __builtin_amdgcn_exp2f(x)
#else
#define FAST_EXP2(x) exp2f(x)
#endif
#if __has_builtin(__builtin_amdgcn_rcpf)
#define FAST_RCP(x) __builtin_amdgcn_rcpf(x)
#else
#define FAST_RCP(x) __fdividef(1.f, (x))
#endif

typedef short bf16x8 __attribute__((ext_vector_type(8)));
typedef float f32x4 __attribute__((ext_vector_type(4)));

typedef __attribute__((address_space(3))) void       as3_void;
typedef __attribute__((address_space(1))) const void as1_cvoid;

// ---- fragment-tiled layout geometry ---------------------------------------
#define KT_T (TEXT_DIM / 32)     // 24 k-tiles (text)
#define KT_I (IMAGE_DIM / 32)    // 32 k-tiles (image)
#define MT_T (B * T / 16)        // 64 m-tiles (text rows)
#define MT_I (B * I_TOK / 16)    // 98 m-tiles (image rows)
#define NT   (HIDDEN / 16)       // 32 n-tiles (W columns)

#define XT_ELEMS (MT_T * KT_T * 512)       // 786432
#define XI_ELEMS (MT_I * KT_I * 512)       // 1605632
#define X_ELEMS  (XT_ELEMS + XI_ELEMS)
#define WT_T_ELEMS (NT * KT_T * 512)       // 393216
#define W_ELEMS (WT_T_ELEMS + NT * KT_I * 512)

#define XTILES_T (MT_T * KT_T)             // 1536
#define XTILES   (XTILES_T + MT_I * KT_I)  // 4672
#define WTILES_T (NT * KT_T)               // 768
#define WTILES   (WTILES_T + NT * KT_I)    // 1792
#define PREP_GRID ((XTILES + WTILES) / 4)  // 1616 blocks, 1 tile per wave

__device__ __forceinline__ unsigned short f2bf(float x) {
    unsigned int u = __float_as_uint(x);
    unsigned int r = u + 0x7FFFu + ((u >> 16) & 1u);   // RNE
    return (unsigned short)(r >> 16);
}
__device__ __forceinline__ float bf2f(unsigned short h) {
    return __uint_as_float(((unsigned int)h) << 16);
}

// ---------------- prep v9: split-bf16 + fragment-tiling (unchanged) --------
__global__ __launch_bounds__(256) void prep_kernel(
        const float* __restrict__ text, const float* __restrict__ image,
        const float* __restrict__ Wt, const float* __restrict__ Wi,
        unsigned short* __restrict__ Xh, unsigned short* __restrict__ Xl,
        unsigned short* __restrict__ WTh, unsigned short* __restrict__ WTl)
{
    const int tid = threadIdx.x;
    const int lane = tid & 63, wv = tid >> 6;
    const int r16 = lane & 15, quad = lane >> 4;
    const int id = blockIdx.x * 4 + wv;

    float v[8];
    unsigned short* oh;
    unsigned short* ol;
    long dst;

    if (id < XTILES) {
        const float* X; int K, mt, kt;
        if (id < XTILES_T) { X = text; K = TEXT_DIM; mt = id / KT_T; kt = id % KT_T; }
        else { const int i2 = id - XTILES_T; X = image; K = IMAGE_DIM; mt = i2 / KT_I; kt = i2 % KT_I; }
        const float* src = X + (long)(mt * 16 + r16) * K + kt * 32 + quad * 8;
        const float4 a = *(const float4*)src;
        const float4 b = *(const float4*)(src + 4);
        v[0]=a.x; v[1]=a.y; v[2]=a.z; v[3]=a.w; v[4]=b.x; v[5]=b.y; v[6]=b.z; v[7]=b.w;
        oh = (id < XTILES_T) ? Xh : Xh + XT_ELEMS;
        ol = (id < XTILES_T) ? Xl : Xl + XT_ELEMS;
        const long tile = (id < XTILES_T) ? id : (long)(id - XTILES_T);
        dst = tile * 512 + lane * 8;
    } else {
        const int idw = id - XTILES;
        const float* W; int K, nt, kt;
        if (idw < WTILES_T) { W = Wt; K = TEXT_DIM; nt = idw / KT_T; kt = idw % KT_T; }
        else { const int i2 = idw - WTILES_T; W = Wi; K = IMAGE_DIM; nt = i2 / KT_I; kt = i2 % KT_I; }
        const float* src = W + (long)(kt * 32 + quad * 8) * HIDDEN + nt * 16 + r16;
        #pragma unroll
        for (int j = 0; j < 8; ++j) v[j] = src[(long)j * HIDDEN];
        oh = (idw < WTILES_T) ? WTh : WTh + WT_T_ELEMS;
        ol = (idw < WTILES_T) ? WTl : WTl + WT_T_ELEMS;
        const long tile = (idw < WTILES_T) ? idw : (long)(idw - WTILES_T);
        dst = tile * 512 + lane * 8;
    }

    uint4 hv, lv;
    unsigned int hh[8], ll[8];
    #pragma unroll
    for (int j = 0; j < 8; ++j) {
        hh[j] = f2bf(v[j]);
        ll[j] = f2bf(v[j] - bf2f((unsigned short)hh[j]));
    }
    hv.x = hh[0] | (hh[1] << 16); hv.y = hh[2] | (hh[3] << 16);
    hv.z = hh[4] | (hh[5] << 16); hv.w = hh[6] | (hh[7] << 16);
    lv.x = ll[0] | (ll[1] << 16); lv.y = ll[2] | (ll[3] << 16);
    lv.z = ll[4] | (ll[5] << 16); lv.w = ll[6] | (ll[7] << 16);
    *(uint4*)(oh + dst) = hv;
    *(uint4*)(ol + dst) = lv;
}

// ---------------- MFMA projections v13: 8-wave blocks (TLP x2) -------------
// R7 audit: proj was the thinnest kernel on chip (328 blocks x 4 waves =
// 1.3 waves/SIMD). Same 64x64 tile, same LDS/pipeline, but 512 threads in a
// 2x4 wave grid: each wave 2 m-tiles x 1 n-tile (6 MFMA/step), stages 2
// tiles/step, vmcnt ladder 6/4/2/0. ~2.6 waves/SIMD. Per-accumulator k-step
// and product order (hh, h*l, l*h) unchanged -> bit-identical.
#define GT2_BLOCKS (16 * 8)                  // 128 (text: 16 m-groups x 8 n)
#define GI2_BLOCKS (25 * 8)                  // 200 (image: 25 m-groups x 8 n)
#define GEMM_GRID (GT2_BLOCKS + GI2_BLOCKS)  // 328

__global__ __launch_bounds__(512, 4) void mfma_proj_kernel(
        const unsigned short* __restrict__ Xh, const unsigned short* __restrict__ Xl,
        const unsigned short* __restrict__ WTh, const unsigned short* __restrict__ WTl,
        const float* __restrict__ bt, const float* __restrict__ bi,
        float* __restrict__ pt, float* __restrict__ pi)
{
    // slots 0-3: Ah(mt0..mt0+3)  4-7: Al  8-11: Bh(nt0..nt0+3)  12-15: Bl
    __shared__ __align__(16) unsigned short lds[4][16][512];   // 64 KB

    const int tid = threadIdx.x;
    const int lane = tid & 63, wv = tid >> 6;        // wv in 0..7
    const int r16 = lane & 15, quad = lane >> 4;
    const int wr = wv >> 2, wc = wv & 3;             // 2x4 wave grid

    // XCD-aware bijective swizzle
    const int bid0 = blockIdx.x;
    int bid;
    if (bid0 < GT2_BLOCKS) bid = (bid0 & 7) * 16 + (bid0 >> 3);
    else { const int d = bid0 - GT2_BLOCKS; bid = GT2_BLOCKS + (d & 7) * 25 + (d >> 3); }

    const unsigned short *xh, *xl, *wh, *wl; const float* bias; float* Y;
    int ktiles, mt0, n8;
    if (bid < GT2_BLOCKS) {
        xh = Xh; xl = Xl; wh = WTh; wl = WTl; bias = bt; Y = pt; ktiles = KT_T;
        mt0 = (bid >> 3) * 4; n8 = bid & 7;
    } else {
        const int ib = bid - GT2_BLOCKS;
        xh = Xh + XT_ELEMS; xl = Xl + XT_ELEMS;
        wh = WTh + WT_T_ELEMS; wl = WTl + WT_T_ELEMS;
        bias = bi; Y = pi; ktiles = KT_I;
        const int mg = ib >> 3;
        mt0 = (mg == 24) ? (MT_I - 4) : mg * 4;   // tail overlaps (bit-identical)
        n8 = ib & 7;
    }
    const int nt0 = n8 * 4;

    // per-wave staging sources: 2 tiles each (t = wv*2, wv*2+1)
    const unsigned short* ssrc[2];
    #pragma unroll
    for (int q = 0; q < 2; ++q) {
        const int t = wv * 2 + q;
        const int g = t >> 2;            // 0:Ah 1:Al 2:Bh 3:Bl
        const int i = t & 3;
        const unsigned short* base = (g == 0) ? xh : (g == 1) ? xl : (g == 2) ? wh : wl;
        const long row = (g < 2) ? (long)(mt0 + i) : (long)(nt0 + i);
        ssrc[q] = base + row * ktiles * 512 + lane * 8;
    }

#define STAGE(buf, kt) do {                                                    \
        _Pragma("unroll")                                                      \
        for (int q_ = 0; q_ < 2; ++q_) {                                       \
            __builtin_amdgcn_global_load_lds(                                  \
                (as1_cvoid*)(ssrc[q_] + (long)(kt) * 512),                     \
                (as3_void*)&lds[buf][wv * 2 + q_][0], 16, 0, 0);               \
        } } while (0)

    f32x4 a0 = {0,0,0,0}, a1 = {0,0,0,0};

    // prologue: 4 stages in flight (ktiles is 24 or 32, always >= 4)
    STAGE(0, 0);
    STAGE(1, 1);
    STAGE(2, 2);
    STAGE(3, 3);

    for (int s = 0; s < ktiles; ++s) {
        // stage s must be complete; up to 3 later stages (2 loads each) fly
        if (s + 3 < ktiles)      asm volatile("s_waitcnt vmcnt(6)" ::: "memory");
        else if (s + 2 < ktiles) asm volatile("s_waitcnt vmcnt(4)" ::: "memory");
        else if (s + 1 < ktiles) asm volatile("s_waitcnt vmcnt(2)" ::: "memory");
        else                     asm volatile("s_waitcnt vmcnt(0)" ::: "memory");
        __builtin_amdgcn_s_barrier();      // all waves' stage-s data visible

        const int cur = s & 3;
        const int fo = lane * 8;
        const bf16x8 Ah0 = *(const bf16x8*)&lds[cur][wr * 2 + 0][fo];
        const bf16x8 Ah1 = *(const bf16x8*)&lds[cur][wr * 2 + 1][fo];
        const bf16x8 Al0 = *(const bf16x8*)&lds[cur][4 + wr * 2 + 0][fo];
        const bf16x8 Al1 = *(const bf16x8*)&lds[cur][4 + wr * 2 + 1][fo];
        const bf16x8 Bh  = *(const bf16x8*)&lds[cur][8 + wc][fo];
        const bf16x8 Bl  = *(const bf16x8*)&lds[cur][12 + wc][fo];

        a0 = __builtin_amdgcn_mfma_f32_16x16x32_bf16(Ah0, Bh, a0, 0, 0, 0);
        a1 = __builtin_amdgcn_mfma_f32_16x16x32_bf16(Ah1, Bh, a1, 0, 0, 0);
        a0 = __builtin_amdgcn_mfma_f32_16x16x32_bf16(Ah0, Bl, a0, 0, 0, 0);
        a1 = __builtin_amdgcn_mfma_f32_16x16x32_bf16(Ah1, Bl, a1, 0, 0, 0);
        a0 = __builtin_amdgcn_mfma_f32_16x16x32_bf16(Al0, Bh, a0, 0, 0, 0);
        a1 = __builtin_amdgcn_mfma_f32_16x16x32_bf16(Al1, Bh, a1, 0, 0, 0);

        __builtin_amdgcn_s_barrier();      // all waves done reading buf cur
        if (s + 4 < ktiles) STAGE(cur, s + 4);
    }
#undef STAGE

    // epilogue: bias + exp2 + store; wave covers 32 rows x 16 cols
    const int row00 = (mt0 + wr * 2) * 16 + quad * 4;
    const int col0  = (nt0 + wc) * 16 + r16;
    const float bv = bias[col0];
    #pragma unroll
    for (int r = 0; r < 4; ++r) {
        Y[(long)(row00 + r)      * HIDDEN + col0] = FAST_EXP2((a0[r] + bv) * EXP_SCALE);
        Y[(long)(row00 + 16 + r) * HIDDEN + col0] = FAST_EXP2((a1[r] + bv) * EXP_SCALE);
    }
}

// ---------------- Scores v10 (unchanged from R6) ---------------------------
__global__ __launch_bounds__(256, 6) void scores_kernel(const float* __restrict__ pt,
        const float* __restrict__ pi, const float* __restrict__ wa,
        const float* __restrict__ ba, float* __restrict__ scores)
{
    const int blk = blockIdx.x;              // 0..2047
    const int chunk = blk & 3;
    const int bt0 = (blk >> 2) * 2;          // even text-row index
    const int b = bt0 >> 7;                  // /T
    const int tid = threadIdx.x;
    const int lane = tid & 63, wave = tid >> 6;

    const float* ptrow = pt + (long)bt0 * HIDDEN + lane * 8;
    const float4 pA0 = *(const float4*)ptrow;
    const float4 pB0 = *(const float4*)(ptrow + 4);
    const float4 pA1 = *(const float4*)(ptrow + HIDDEN);
    const float4 pB1 = *(const float4*)(ptrow + HIDDEN + 4);
    float4 wA = *(const float4*)(wa + lane * 8);
    float4 wB = *(const float4*)(wa + lane * 8 + 4);

    float S = wA.x + wA.y + wA.z + wA.w + wB.x + wB.y + wB.z + wB.w;
    #pragma unroll
    for (int off = 32; off; off >>= 1) S += __shfl_down(S, off);
    const float base = S + ba[0];

    wA.x *= -2.f; wA.y *= -2.f; wA.z *= -2.f; wA.w *= -2.f;
    wB.x *= -2.f; wB.y *= -2.f; wB.z *= -2.f; wB.w *= -2.f;

    const float* pib = pi + (long)b * I_TOK * HIDDEN + lane * 8;
    const int i0 = chunk * 49 + wave;
    const int iend = chunk * 49 + 49;

    float4 ca = *(const float4*)(pib + (long)i0 * HIDDEN);
    float4 cb = *(const float4*)(pib + (long)i0 * HIDDEN + 4);

    for (int i = i0; i < iend; i += 4) {
        const int inx = (i + 4 < iend) ? (i + 4) : i;
        const float4 na = *(const float4*)(pib + (long)inx * HIDDEN);
        const float4 nb = *(const float4*)(pib + (long)inx * HIDDEN + 4);

        float acc0 = 0.f;
        acc0 = fmaf(wA.x, FAST_RCP(fmaf(pA0.x, ca.x, 1.f)), acc0);
        acc0 = fmaf(wA.y, FAST_RCP(fmaf(pA0.y, ca.y, 1.f)), acc0);
        acc0 = fmaf(wA.z, FAST_RCP(fmaf(pA0.z, ca.z, 1.f)), acc0);
        acc0 = fmaf(wA.w, FAST_RCP(fmaf(pA0.w, ca.w, 1.f)), acc0);
        acc0 = fmaf(wB.x, FAST_RCP(fmaf(pB0.x, cb.x, 1.f)), acc0);
        acc0 = fmaf(wB.y, FAST_RCP(fmaf(pB0.y, cb.y, 1.f)), acc0);
        acc0 = fmaf(wB.z, FAST_RCP(fmaf(pB0.z, cb.z, 1.f)), acc0);
        acc0 = fmaf(wB.w, FAST_RCP(fmaf(pB0.w, cb.w, 1.f)), acc0);

        float acc1 = 0.f;
        acc1 = fmaf(wA.x, FAST_RCP(fmaf(pA1.x, ca.x, 1.f)), acc1);
        acc1 = fmaf(wA.y, FAST_RCP(fmaf(pA1.y, ca.y, 1.f)), acc1);
        acc1 = fmaf(wA.z, FAST_RCP(fmaf(pA1.z, ca.z, 1.f)), acc1);
        acc1 = fmaf(wA.w, FAST_RCP(fmaf(pA1.w, ca.w, 1.f)), acc1);
        acc1 = fmaf(wB.x, FAST_RCP(fmaf(pB1.x, cb.x, 1.f)), acc1);
        acc1 = fmaf(wB.y, FAST_RCP(fmaf(pB1.y, cb.y, 1.f)), acc1);
        acc1 = fmaf(wB.z, FAST_RCP(fmaf(pB1.z, cb.z, 1.f)), acc1);
        acc1 = fmaf(wB.w, FAST_RCP(fmaf(pB1.w, cb.w, 1.f)), acc1);

        #pragma unroll
        for (int off = 32; off; off >>= 1) {
            acc0 += __shfl_down(acc0, off);
            acc1 += __shfl_down(acc1, off);
        }
        if (lane == 0) {
            scores[(long)bt0 * I_TOK + i]       = base + acc0;
            scores[(long)(bt0 + 1) * I_TOK + i] = base + acc1;
        }
        ca = na; cb = nb;
    }
}

// ---------------- Fused attended outputs v11 (unchanged from R7) -----------
#define ATT_P1_BLOCKS 512                    // 8b * 16 grp * 4 csplit
#define ATT_P2_BLOCKS (B * 28)               // 196 = 28 * 7
#define ATT_GRID (ATT_P1_BLOCKS + ATT_P2_BLOCKS)   // 736

__global__ __launch_bounds__(256) void att_kernel(const float* __restrict__ scores,
        const float* __restrict__ image, const float* __restrict__ text,
        float* __restrict__ out_text, float* __restrict__ out_img)
{
    const int tid = threadIdx.x, lane = tid & 63, wave = tid >> 6;

    if (blockIdx.x < ATT_P1_BLOCKS) {
        const int bid = blockIdx.x;
        const int csplit = bid & 3;
        const int grp = bid >> 2;            // 0..127
        const int b = grp >> 4;
        const int t0 = (grp & 15) * 8;

        __shared__ float ps[I_TOK][8];
        #pragma unroll
        for (int rr = 0; rr < 2; ++rr) {
            const int tsub = wave + rr * 4;
            const float* srow = scores + ((long)(b * T + t0 + tsub)) * I_TOK;
            const float s0 = srow[lane];
            const float s1 = srow[lane + 64];
            const float s2 = srow[lane + 128];
            const float s3 = (lane < 4) ? srow[lane + 192] : -INFINITY;
            float m = fmaxf(fmaxf(s0, s1), fmaxf(s2, s3));
            #pragma unroll
            for (int off = 32; off; off >>= 1) m = fmaxf(m, __shfl_xor(m, off));
            const float e0 = __expf(s0 - m);
            const float e1 = __expf(s1 - m);
            const float e2 = __expf(s2 - m);
            const float e3 = (lane < 4) ? __expf(s3 - m) : 0.f;
            float sum = e0 + e1 + e2 + e3;
            #pragma unroll
            for (int off = 32; off; off >>= 1) sum += __shfl_xor(sum, off);
            const float inv = __fdividef(1.0f, sum);
            ps[lane][tsub] = e0 * inv;
            ps[lane + 64][tsub] = e1 * inv;
            ps[lane + 128][tsub] = e2 * inv;
            if (lane < 4) ps[lane + 192][tsub] = e3 * inv;
        }
        __syncthreads();

        const float* img = image + (long)b * I_TOK * IMAGE_DIM + csplit * 256 + tid;
        float a0 = 0.f, a1 = 0.f, a2 = 0.f, a3 = 0.f;
        float a4 = 0.f, a5 = 0.f, a6 = 0.f, a7 = 0.f;

        // 3-set image-row pipeline (2-deep prefetch), 1 col/thread
        float vA0 = img[0 * IMAGE_DIM];
        float vA1 = img[1 * IMAGE_DIM];
        float vA2 = img[2 * IMAGE_DIM];
        float vA3 = img[3 * IMAGE_DIM];
        float vB0 = img[4 * IMAGE_DIM];
        float vB1 = img[5 * IMAGE_DIM];
        float vB2 = img[6 * IMAGE_DIM];
        float vB3 = img[7 * IMAGE_DIM];
        float4 pL0 = *(const float4*)&ps[0][0]; float4 pH0 = *(const float4*)&ps[0][4];
        float4 pL1 = *(const float4*)&ps[1][0]; float4 pH1 = *(const float4*)&ps[1][4];
        float4 pL2 = *(const float4*)&ps[2][0]; float4 pH2 = *(const float4*)&ps[2][4];
        float4 pL3 = *(const float4*)&ps[3][0]; float4 pH3 = *(const float4*)&ps[3][4];

        for (int g = 0; g < 49; ++g) {
            const int ib2 = ((g + 2 < 49) ? (g + 2) : 48) * 4;   // 2-ahead (clamped)
            const float t0_ = img[(long)(ib2 + 0) * IMAGE_DIM];
            const float t1_ = img[(long)(ib2 + 1) * IMAGE_DIM];
            const float t2_ = img[(long)(ib2 + 2) * IMAGE_DIM];
            const float t3_ = img[(long)(ib2 + 3) * IMAGE_DIM];
            const int ibn = ((g + 1 < 49) ? (g + 1) : 48) * 4;   // LDS 1-ahead
            const float4 nL0 = *(const float4*)&ps[ibn + 0][0]; const float4 nH0 = *(const float4*)&ps[ibn + 0][4];
            const float4 nL1 = *(const float4*)&ps[ibn + 1][0]; const float4 nH1 = *(const float4*)&ps[ibn + 1][4];
            const float4 nL2 = *(const float4*)&ps[ibn + 2][0]; const float4 nH2 = *(const float4*)&ps[ibn + 2][4];
            const float4 nL3 = *(const float4*)&ps[ibn + 3][0]; const float4 nH3 = *(const float4*)&ps[ibn + 3][4];

#define ATT_ROW(vr, pl, ph)                                                   \
            a0 = fmaf(pl.x, vr, a0); a1 = fmaf(pl.y, vr, a1);                 \
            a2 = fmaf(pl.z, vr, a2); a3 = fmaf(pl.w, vr, a3);                 \
            a4 = fmaf(ph.x, vr, a4); a5 = fmaf(ph.y, vr, a5);                 \
            a6 = fmaf(ph.z, vr, a6); a7 = fmaf(ph.w, vr, a7);
            ATT_ROW(vA0, pL0, pH0)
            ATT_ROW(vA1, pL1, pH1)
            ATT_ROW(vA2, pL2, pH2)
            ATT_ROW(vA3, pL3, pH3)
#undef ATT_ROW
            vA0 = vB0; vA1 = vB1; vA2 = vB2; vA3 = vB3;
            vB0 = t0_; vB1 = t1_; vB2 = t2_; vB3 = t3_;
            pL0 = nL0; pH0 = nH0; pL1 = nL1; pH1 = nH1;
            pL2 = nL2; pH2 = nH2; pL3 = nL3; pH3 = nH3;
        }
        float* o = out_text + ((long)(b * T + t0)) * IMAGE_DIM + csplit * 256 + tid;
        o[0 * IMAGE_DIM] = a0;
        o[1 * IMAGE_DIM] = a1;
        o[2 * IMAGE_DIM] = a2;
        o[3 * IMAGE_DIM] = a3;
        o[4 * IMAGE_DIM] = a4;
        o[5 * IMAGE_DIM] = a5;
        o[6 * IMAGE_DIM] = a6;
        o[7 * IMAGE_DIM] = a7;
    } else {
        const int bid = blockIdx.x - ATT_P1_BLOCKS;
        const int b = bid / 28;
        const int i0 = (bid % 28) * 7;

        __shared__ float qs[T][8];           // col 7 is padding
        for (int cc = wave; cc < 7; cc += 4) {
            const float* sc = scores + (long)b * T * I_TOK + (i0 + cc);
            const float s0 = sc[(long)lane * I_TOK];
            const float s1 = sc[(long)(lane + 64) * I_TOK];
            float m = fmaxf(s0, s1);
            #pragma unroll
            for (int off = 32; off; off >>= 1) m = fmaxf(m, __shfl_xor(m, off));
            const float e0 = __expf(s0 - m);
            const float e1 = __expf(s1 - m);
            float sum = e0 + e1;
            #pragma unroll
            for (int off = 32; off; off >>= 1) sum += __shfl_xor(sum, off);
            const float inv = __fdividef(1.0f, sum);
            qs[lane][cc] = e0 * inv;
            qs[lane + 64][cc] = e1 * inv;
        }
        __syncthreads();

        const float* txt2 = text + (long)b * T * TEXT_DIM + tid * 2;
        const float* txt1 = text + (long)b * T * TEXT_DIM + 512 + tid;
        float ax[7], ay[7], az[7];
        #pragma unroll
        for (int r = 0; r < 7; ++r) { ax[r] = 0.f; ay[r] = 0.f; az[r] = 0.f; }

        // 3-set text-row pipeline (2-deep prefetch)
        float2 uA0 = *(const float2*)(txt2 + 0 * TEXT_DIM);
        float2 uA1 = *(const float2*)(txt2 + 1 * TEXT_DIM);
        float  zA0 = txt1[0 * TEXT_DIM];
        float  zA1 = txt1[1 * TEXT_DIM];
        float2 uB0 = *(const float2*)(txt2 + 2 * TEXT_DIM);
        float2 uB1 = *(const float2*)(txt2 + 3 * TEXT_DIM);
        float  zB0 = txt1[2 * TEXT_DIM];
        float  zB1 = txt1[3 * TEXT_DIM];
        float4 qa0 = *(const float4*)&qs[0][0]; float4 qb0 = *(const float4*)&qs[0][4];
        float4 qa1 = *(const float4*)&qs[1][0]; float4 qb1 = *(const float4*)&qs[1][4];

        for (int g = 0; g < 64; ++g) {
            const int tb2 = ((g + 2 < 64) ? (g + 2) : 63) * 2;   // 2-ahead (clamped)
            const float2 tu0 = *(const float2*)(txt2 + (long)(tb2 + 0) * TEXT_DIM);
            const float2 tu1 = *(const float2*)(txt2 + (long)(tb2 + 1) * TEXT_DIM);
            const float  tz0 = txt1[(long)(tb2 + 0) * TEXT_DIM];
            const float  tz1 = txt1[(long)(tb2 + 1) * TEXT_DIM];
            const int tbn = ((g + 1 < 64) ? (g + 1) : 63) * 2;   // LDS 1-ahead
            const float4 na0 = *(const float4*)&qs[tbn + 0][0];
            const float4 nb0 = *(const float4*)&qs[tbn + 0][4];
            const float4 na1 = *(const float4*)&qs[tbn + 1][0];
            const float4 nb1 = *(const float4*)&qs[tbn + 1][4];

            // row 2g
            ax[0] = fmaf(qa0.x, uA0.x, ax[0]); ay[0] = fmaf(qa0.x, uA0.y, ay[0]); az[0] = fmaf(qa0.x, zA0, az[0]);
            ax[1] = fmaf(qa0.y, uA0.x, ax[1]); ay[1] = fmaf(qa0.y, uA0.y, ay[1]); az[1] = fmaf(qa0.y, zA0, az[1]);
            ax[2] = fmaf(qa0.z, uA0.x, ax[2]); ay[2] = fmaf(qa0.z, uA0.y, ay[2]); az[2] = fmaf(qa0.z, zA0, az[2]);
            ax[3] = fmaf(qa0.w, uA0.x, ax[3]); ay[3] = fmaf(qa0.w, uA0.y, ay[3]); az[3] = fmaf(qa0.w, zA0, az[3]);
            ax[4] = fmaf(qb0.x, uA0.x, ax[4]); ay[4] = fmaf(qb0.x, uA0.y, ay[4]); az[4] = fmaf(qb0.x, zA0, az[4]);
            ax[5] = fmaf(qb0.y, uA0.x, ax[5]); ay[5] = fmaf(qb0.y, uA0.y, ay[5]); az[5] = fmaf(qb0.y, zA0, az[5]);
            ax[6] = fmaf(qb0.z, uA0.x, ax[6]); ay[6] = fmaf(qb0.z, uA0.y, ay[6]); az[6] = fmaf(qb0.z, zA0, az[6]);
            // row 2g+1
            ax[0] = fmaf(qa1.x, uA1.x, ax[0]); ay[0] = fmaf(qa1.x, uA1.y, ay[0]); az[0] = fmaf(qa1.x, zA1, az[0]);
            ax[1] = fmaf(qa1.y, uA1.x, ax[1]); ay[1] = fmaf(qa1.y, uA1.y, ay[1]); az[1] = fmaf(qa1.y, zA1, az[1]);
            ax[2] = fmaf(qa1.z, uA1.x, ax[2]); ay[2] = fmaf(qa1.z, uA1.y, ay[2]); az[2] = fmaf(qa1.z, zA1, az[2]);
            ax[3] = fmaf(qa1.w, uA1.x, ax[3]); ay[3] = fmaf(qa1.w, uA1.y, ay[3]); az[3] = fmaf(qa1.w, zA1, az[3]);
            ax[4] = fmaf(qb1.x, uA1.x, ax[4]); ay[4] = fmaf(qb1.x, uA1.y, ay[4]); az[4] = fmaf(qb1.x, zA1, az[4]);
            ax[5] = fmaf(qb1.y, uA1.x, ax[5]); ay[5] = fmaf(qb1.y, uA1.y, ay[5]); az[5] = fmaf(qb1.y, zA1, az[5]);
            ax[6] = fmaf(qb1.z, uA1.x, ax[6]); ay[6] = fmaf(qb1.z, uA1.y, ay[6]); az[6] = fmaf(qb1.z, zA1, az[6]);

            uA0 = uB0; uA1 = uB1; zA0 = zB0; zA1 = zB1;
            uB0 = tu0; uB1 = tu1; zB0 = tz0; zB1 = tz1;
            qa0 = na0; qb0 = nb0; qa1 = na1; qb1 = nb1;
        }
        float* o = out_img + ((long)b * I_TOK + i0) * TEXT_DIM;
        #pragma unroll
        for (int r = 0; r < 7; ++r) {
            float2 w;
            w.x = ax[r]; w.y = ay[r];
            *(float2*)(o + (long)r * TEXT_DIM + tid * 2) = w;
            o[(long)r * TEXT_DIM + 512 + tid] = az[r];
        }
    }
}

extern "C" void kernel_launch(void* const* d_in, const int* in_sizes, int n_in,
                              void* d_out, int out_size, void* d_ws, size_t ws_size,
                              hipStream_t stream) {
    const float* text  = (const float*)d_in[0];
    const float* image = (const float*)d_in[1];
    const float* Wt    = (const float*)d_in[2];
    const float* bt    = (const float*)d_in[3];
    const float* Wi    = (const float*)d_in[4];
    const float* bi    = (const float*)d_in[5];
    const float* wa    = (const float*)d_in[6];
    const float* ba    = (const float*)d_in[7];

    float* pt = (float*)d_ws;                       // Et = exp2-transformed
    float* pi = pt + (long)B * T * HIDDEN;          // Ei
    float* sc = pi + (long)B * I_TOK * HIDDEN;
    unsigned short* Xh  = (unsigned short*)(sc + (long)B * T * I_TOK);
    unsigned short* Xl  = Xh + X_ELEMS;
    unsigned short* WTh = Xl + X_ELEMS;
    unsigned short* WTl = WTh + W_ELEMS;

    float* out_text = (float*)d_out;                        // B*T*IMAGE_DIM
    float* out_img  = out_text + (long)B * T * IMAGE_DIM;   // B*I*TEXT_DIM

    prep_kernel<<<PREP_GRID, 256, 0, stream>>>(text, image, Wt, Wi, Xh, Xl, WTh, WTl);
    mfma_proj_kernel<<<GEMM_GRID, 512, 0, stream>>>(Xh, Xl, WTh, WTl, bt, bi, pt, pi);
    scores_kernel<<<2 * B * T, 256, 0, stream>>>(pt, pi, wa, ba, sc);
    att_kernel<<<ATT_GRID, 256, 0, stream>>>(sc, image, text, out_text, out_img);
}